// Round 13
// baseline (2419.503 us; speedup 1.0000x reference)
//
#include <hip/hip_runtime.h>
#include <math.h>

#define NND 50000
#define NED 800000
#define HD  128
#define NG  64
#define MTO 16

typedef __attribute__((ext_vector_type(8))) short short8v;
typedef __attribute__((ext_vector_type(4))) float float4v;
typedef __attribute__((ext_vector_type(2))) float float2v;

__device__ __forceinline__ float gelu_t(float x) {
  const float c = 0.7978845608028654f;
  float t = tanhf(c * (x + 0.044715f * x * x * x));
  return 0.5f * x * (1.0f + t);
}

__device__ __forceinline__ unsigned short f2bf(float f) {
  unsigned int u = __float_as_uint(f);
  u += 0x7FFFu + ((u >> 16) & 1u);
  return (unsigned short)(u >> 16);
}
__device__ __forceinline__ float bf2f(unsigned short s) {
  return __uint_as_float(((unsigned int)s) << 16);
}
__device__ __forceinline__ float bflo(unsigned int u) { return __uint_as_float(u << 16); }
__device__ __forceinline__ float bfhi(unsigned int u) { return __uint_as_float(u & 0xFFFF0000u); }

// ---------------- CSR build ----------------
__global__ void k_hist(const int* __restrict__ dst, int* __restrict__ degi) {
  int e = blockIdx.x * 256 + threadIdx.x;
  if (e < NED) atomicAdd(&degi[dst[e]], 1);
}

__global__ __launch_bounds__(1024) void k_scan(
    const int* __restrict__ degi, int* __restrict__ rowptr,
    int* __restrict__ cursor, float* __restrict__ deginv) {
  __shared__ int wsum[16];
  int tid = threadIdx.x;
  int lane = tid & 63;
  int wid = tid >> 6;
  int running = 0;
  for (int base = 0; base < NND; base += 1024) {
    int idx = base + tid;
    int v = (idx < NND) ? degi[idx] : 0;
    int s = v;
#pragma unroll
    for (int o = 1; o < 64; o <<= 1) {
      int t = __shfl_up(s, o, 64);
      if (lane >= o) s += t;
    }
    if (lane == 63) wsum[wid] = s;
    __syncthreads();
    if (wid == 0) {
      int ws = (lane < 16) ? wsum[lane] : 0;
#pragma unroll
      for (int o = 1; o < 16; o <<= 1) {
        int t = __shfl_up(ws, o, 64);
        if (lane >= o) ws += t;
      }
      if (lane < 16) wsum[lane] = ws;
    }
    __syncthreads();
    int woff = wid ? wsum[wid - 1] : 0;
    int excl = running + woff + s - v;
    if (idx < NND) {
      rowptr[idx] = excl;
      cursor[idx] = excl;
      deginv[idx] = 1.0f / (float)max(v, 1);
    }
    int tot = wsum[15];
    __syncthreads();
    running += tot;
  }
  if (tid == 0) rowptr[NND] = running;
}

__global__ void k_scatter(const int* __restrict__ src, const int* __restrict__ dst,
                          int* __restrict__ cursor, unsigned short* __restrict__ cs16) {
  int e = blockIdx.x * 256 + threadIdx.x;
  if (e < NED) {
    int d = dst[e];
    int pos = atomicAdd(&cursor[d], 1);
    cs16[pos] = (unsigned short)src[e];
  }
}

// cnt + contiguous row ranges per graph (batch is sorted)
__global__ void k_cnt(const int* __restrict__ batch, float* __restrict__ cnt,
                      int* __restrict__ rowstart) {
  int g = threadIdx.x;
  if (g >= NG) return;
  int lo = 0, hi = NND;
  while (lo < hi) { int mid = (lo + hi) >> 1; if (batch[mid] <= g) lo = mid + 1; else hi = mid; }
  int ub_g = lo;
  int ub_gm1 = 0;
  if (g > 0) {
    lo = 0; hi = NND;
    int v = g - 1;
    while (lo < hi) { int mid = (lo + hi) >> 1; if (batch[mid] <= v) lo = mid + 1; else hi = mid; }
    ub_gm1 = lo;
  }
  cnt[g] = (float)(ub_g - ub_gm1);
  rowstart[g + 1] = ub_g;
  if (g == 0) rowstart[0] = 0;
}

// weffT[n][k] = bf16(Wint[k][n] + Wint[k+128][n])
__global__ void k_weffT(const float* __restrict__ Wint, unsigned short* __restrict__ weffT) {
  int i = blockIdx.x * 256 + threadIdx.x;
  if (i < 128 * 128) {
    int n = i >> 7, k = i & 127;
    weffT[i] = f2bf(Wint[k * 128 + n] + Wint[(k + 128) * 128 + n]);
  }
}

__global__ void k_prepB(const float* __restrict__ Wself, const float* __restrict__ Wmsg,
                        unsigned short* __restrict__ Bt) {
  int i = blockIdx.x * 256 + threadIdx.x;
  if (i < 128 * 256) {
    int n = i >> 8, k = i & 255;
    float w = (k < HD) ? Wself[k * HD + n] : Wmsg[(k - HD) * HD + n];
    Bt[i] = f2bf(w);
  }
}

__global__ void k_prepIn(const float* __restrict__ Win, const float* __restrict__ Walt,
                         unsigned short* __restrict__ BtIn) {
  int i = blockIdx.x * 256 + threadIdx.x;
  if (i < 2 * 128 * 128) {
    int p = i >> 14; int rem = i & 16383; int n = rem >> 7; int k = rem & 127;
    const float* W = p ? Walt : Win;
    BtIn[i] = f2bf(W[k * 128 + n]);
  }
}

// ---------------- init (MFMA): writes hbf only ----------------
__global__ __launch_bounds__(256) void k_init2(
    const float* __restrict__ x, const unsigned short* __restrict__ BtIn,
    const float* __restrict__ bin, const float* __restrict__ gin, const float* __restrict__ bein,
    const float* __restrict__ balt, const float* __restrict__ galt, const float* __restrict__ bealt,
    const float* __restrict__ alphap, const float* __restrict__ betap,
    unsigned short* __restrict__ hbf)
{
  __shared__ float red[4][16][2];
  __shared__ unsigned short gtile[2][16][64];
  int tid = threadIdx.x;
  int wave = tid >> 6;
  int lane = tid & 63;
  int l15 = lane & 15;
  int lhi = lane >> 4;
  int path = wave >> 1;
  int colBase = (wave & 1) * 64;
  int rowBase = blockIdx.x * 64;

  const unsigned short* Bp = BtIn + path * 128 * 128;
  short8v bfr[4][4];
#pragma unroll
  for (int t = 0; t < 4; ++t) {
    int n = colBase + t * 16 + l15;
#pragma unroll
    for (int s = 0; s < 4; ++s)
      bfr[t][s] = *(const short8v*)&Bp[n * 128 + s * 32 + lhi * 8];
  }

  const float* bvp = path ? balt : bin;
  const float* gp  = path ? galt : gin;
  const float* bep = path ? bealt : bein;
  float bv[4], gw[4], bew[4];
#pragma unroll
  for (int t = 0; t < 4; ++t) {
    int col = colBase + t * 16 + l15;
    bv[t] = bvp[col]; gw[t] = gp[col]; bew[t] = bep[col];
  }

  float al = alphap[0], btv = betap[0];
  float nrm = sqrtf(al * al + btv * btv);
  float w0 = fabsf(al) / nrm, w1 = fabsf(btv) / nrm;

  for (int rt = 0; rt < 4; ++rt) {
    int arow = rowBase + rt * 16 + l15; if (arow >= NND) arow = NND - 1;
    short8v afr[4];
#pragma unroll
    for (int s = 0; s < 4; ++s) {
      float4 xa = *(const float4*)&x[(size_t)arow * HD + s * 32 + lhi * 8];
      float4 xb = *(const float4*)&x[(size_t)arow * HD + s * 32 + lhi * 8 + 4];
      short8v f;
      f[0] = (short)f2bf(xa.x); f[1] = (short)f2bf(xa.y);
      f[2] = (short)f2bf(xa.z); f[3] = (short)f2bf(xa.w);
      f[4] = (short)f2bf(xb.x); f[5] = (short)f2bf(xb.y);
      f[6] = (short)f2bf(xb.z); f[7] = (short)f2bf(xb.w);
      afr[s] = f;
    }

    float4v acc[4];
#pragma unroll
    for (int t = 0; t < 4; ++t) acc[t] = (float4v){0.f, 0.f, 0.f, 0.f};
#pragma unroll
    for (int s = 0; s < 4; ++s) {
#pragma unroll
      for (int t = 0; t < 4; ++t)
        acc[t] = __builtin_amdgcn_mfma_f32_16x16x32_bf16(afr[s], bfr[t][s], acc[t], 0, 0, 0);
    }

    float z[4][4];
    float psum[4], psq[4];
#pragma unroll
    for (int r = 0; r < 4; ++r) {
      float s1 = 0.f, s2 = 0.f;
#pragma unroll
      for (int t = 0; t < 4; ++t) {
        float zz = acc[t][r] + bv[t];
        z[r][t] = zz;
        s1 += zz; s2 += zz * zz;
      }
#pragma unroll
      for (int m = 1; m < 16; m <<= 1) {
        s1 += __shfl_xor(s1, m, 16);
        s2 += __shfl_xor(s2, m, 16);
      }
      psum[r] = s1; psq[r] = s2;
    }
    if (l15 == 0) {
#pragma unroll
      for (int r = 0; r < 4; ++r) {
        red[wave][lhi * 4 + r][0] = psum[r];
        red[wave][lhi * 4 + r][1] = psq[r];
      }
    }
    __syncthreads();

    int pw = wave ^ 1;
    float gval[4][4];
#pragma unroll
    for (int r = 0; r < 4; ++r) {
      int rowl = lhi * 4 + r;
      float S = psum[r] + red[pw][rowl][0];
      float Q = psq[r]  + red[pw][rowl][1];
      float mean = S * (1.0f / 128.0f);
      float var  = Q * (1.0f / 128.0f) - mean * mean;
      float rs = rsqrtf(var + 1e-5f);
#pragma unroll
      for (int t = 0; t < 4; ++t)
        gval[r][t] = gelu_t((z[r][t] - mean) * rs * gw[t] + bew[t]);
    }

    if (path == 1) {
#pragma unroll
      for (int r = 0; r < 4; ++r)
#pragma unroll
        for (int t = 0; t < 4; ++t)
          gtile[wave & 1][lhi * 4 + r][t * 16 + l15] = f2bf(gval[r][t]);
    }
    __syncthreads();

    if (path == 0) {
#pragma unroll
      for (int r = 0; r < 4; ++r) {
        int m = rowBase + rt * 16 + lhi * 4 + r;
        if (m < NND) {
#pragma unroll
          for (int t = 0; t < 4; ++t) {
            float g1 = bf2f(gtile[wave & 1][lhi * 4 + r][t * 16 + l15]);
            float hv = w0 * gval[r][t] + w1 * g1;
            hbf[(size_t)m * HD + colBase + t * 16 + l15] = f2bf(hv);
          }
        }
      }
    }
    __syncthreads();
  }
}

// ---------------- gather kernel ----------------
// mode 0: u = meanagg(hbf); usav = u     (step-0 stage-0)
// mode 1: usav += meanagg(dh8)/8; u = usav  (stage-0 later steps)
// mode 2: u = usav + cu*meanagg(t8)         (stages 1-3)
__global__ __launch_bounds__(256) void k_gath2(
    const unsigned short* __restrict__ hbf,
    const unsigned char*  __restrict__ t8,
    unsigned short* __restrict__ usav,
    unsigned short* __restrict__ uT,
    const int* __restrict__ rowptr,
    const unsigned short* __restrict__ cs16,
    const float* __restrict__ deginv,
    int mode, float cu)
{
  int tid = threadIdx.x;
  int l16 = tid & 15;
  int grp = tid >> 4;
  int node = blockIdx.x * 16 + grp;
  if (node >= NND) return;
  int e0 = rowptr[node], e1 = rowptr[node + 1];
  float a0=0,a1=0,a2=0,a3=0,a4=0,a5=0,a6=0,a7=0;

  if (mode == 0) {
    for (int eb = e0; eb < e1; eb += 16) {
      int rem = e1 - eb;
      int ia = eb + l16; if (ia > e1 - 1) ia = e1 - 1;
      int my = cs16[ia];
      int n16 = (rem < 16) ? rem : 16;
#pragma unroll
      for (int j = 0; j < 16; ++j) {
        if (j < n16) {
          int s = __shfl(my, j, 16);
          uint4 v = *(const uint4*)&hbf[(size_t)s * HD + l16 * 8];
          a0 += bflo(v.x); a1 += bfhi(v.x); a2 += bflo(v.y); a3 += bfhi(v.y);
          a4 += bflo(v.z); a5 += bfhi(v.z); a6 += bflo(v.w); a7 += bfhi(v.w);
        }
      }
    }
  } else {
    for (int eb = e0; eb < e1; eb += 16) {
      int rem = e1 - eb;
      int ia = eb + l16; if (ia > e1 - 1) ia = e1 - 1;
      int my = cs16[ia];
      int n16 = (rem < 16) ? rem : 16;
      uint2 v[16];
#pragma unroll
      for (int j = 0; j < 16; ++j) {
        if (j < n16) {
          int s = __shfl(my, j, 16);
          v[j] = *(const uint2*)&t8[(size_t)s * HD + l16 * 8];
        }
      }
#pragma unroll
      for (int j = 0; j < 16; ++j) {
        if (j < n16) {
          float2v f0 = __builtin_amdgcn_cvt_pk_f32_fp8(v[j].x, false);
          float2v f1 = __builtin_amdgcn_cvt_pk_f32_fp8(v[j].x, true);
          float2v f2 = __builtin_amdgcn_cvt_pk_f32_fp8(v[j].y, false);
          float2v f3 = __builtin_amdgcn_cvt_pk_f32_fp8(v[j].y, true);
          a0 += f0[0]; a1 += f0[1]; a2 += f1[0]; a3 += f1[1];
          a4 += f2[0]; a5 += f2[1]; a6 += f3[0]; a7 += f3[1];
        }
      }
    }
  }

  float sc = deginv[node] * ((mode == 0) ? 1.0f : ((mode == 1) ? 0.125f : cu));
  size_t base = (size_t)node * HD + l16 * 8;
  float u0,u1,u2,u3,u4,u5,u6,u7;
  if (mode == 0) {
    u0=a0*sc; u1=a1*sc; u2=a2*sc; u3=a3*sc; u4=a4*sc; u5=a5*sc; u6=a6*sc; u7=a7*sc;
  } else {
    uint4 us = *(const uint4*)&usav[base];
    u0 = bflo(us.x) + a0*sc; u1 = bfhi(us.x) + a1*sc;
    u2 = bflo(us.y) + a2*sc; u3 = bfhi(us.y) + a3*sc;
    u4 = bflo(us.z) + a4*sc; u5 = bfhi(us.z) + a5*sc;
    u6 = bflo(us.w) + a6*sc; u7 = bfhi(us.w) + a7*sc;
  }
  uint4 o;
  o.x = (unsigned int)f2bf(u0) | ((unsigned int)f2bf(u1) << 16);
  o.y = (unsigned int)f2bf(u2) | ((unsigned int)f2bf(u3) << 16);
  o.z = (unsigned int)f2bf(u4) | ((unsigned int)f2bf(u5) << 16);
  o.w = (unsigned int)f2bf(u6) | ((unsigned int)f2bf(u7) << 16);
  if (mode <= 1) *(uint4*)&usav[base] = o;
  *(uint4*)&uT[base] = o;
}

// ---------------- ODE GEMM: MT=16, hoisted loads, no ybf/kacc ----------------
__global__ __launch_bounds__(256) void k_ode4(
    const unsigned short* __restrict__ hc,
    unsigned short* __restrict__ hn,
    const unsigned short* __restrict__ uT,
    const unsigned char* __restrict__ k8A,
    unsigned char* __restrict__ k8w,
    const unsigned char* __restrict__ k8r0,
    const unsigned char* __restrict__ k8r1,
    const unsigned char* __restrict__ k8r2,
    unsigned char* __restrict__ dh8,
    const unsigned short* __restrict__ Bt, const float* __restrict__ bode,
    int stage, float cyA)
{
  int tid = threadIdx.x;
  int wave = tid >> 6;
  int lane = tid & 63;
  int l15 = lane & 15;
  int lhi = lane >> 4;
  int rowBase = blockIdx.x * MTO;
  int ncol0 = wave * 32;

  const float DT = 0.125f;
  const float w6 = DT / 6.0f;

  int m = rowBase + l15;
  int mload = (m < NND) ? m : NND - 1;

  // ---- issue all A/u loads up front ----
  uint4 hraw[4];
  uint2 kraw[4];
  short8v ufr[4];
#pragma unroll
  for (int s = 0; s < 4; ++s) {
    size_t base = (size_t)mload * HD + s * 32 + lhi * 8;
    hraw[s] = *(const uint4*)&hc[base];
    ufr[s] = *(const short8v*)&uT[base];
    if (stage > 0) kraw[s] = *(const uint2*)&k8A[base];
  }

  // ---- stage-3 epilogue preloads (fly under B-load + MFMA) ----
  unsigned int q0[2], q1[2], q2[2];
  uint2 hvp[2];
  if (stage == 3) {
#pragma unroll
    for (int t = 0; t < 2; ++t) {
      size_t off = (size_t)mload * HD + ncol0 + t * 16 + lhi * 4;
      q0[t] = *(const unsigned int*)&k8r0[off];
      q1[t] = *(const unsigned int*)&k8r1[off];
      q2[t] = *(const unsigned int*)&k8r2[off];
      hvp[t] = *(const uint2*)&hc[off];
    }
  }

  // ---- B fragments ----
  short8v bfr[2][8];
#pragma unroll
  for (int t = 0; t < 2; ++t) {
    int n = ncol0 + t * 16 + l15;
#pragma unroll
    for (int s = 0; s < 8; ++s) {
      bfr[t][s] = *(const short8v*)&Bt[n * 256 + s * 32 + lhi * 8];
    }
  }
  float4 bo4[2];
  bo4[0] = *(const float4*)&bode[ncol0 + lhi * 4];
  bo4[1] = *(const float4*)&bode[ncol0 + 16 + lhi * 4];

  // ---- build A fragments ----
  short8v afr[8];
#pragma unroll
  for (int s = 0; s < 4; ++s) {
    if (stage == 0) {
      uint4 hv = hraw[s];
      short8v f;
      f[0] = (short)(unsigned short)(hv.x & 0xFFFF); f[1] = (short)(unsigned short)(hv.x >> 16);
      f[2] = (short)(unsigned short)(hv.y & 0xFFFF); f[3] = (short)(unsigned short)(hv.y >> 16);
      f[4] = (short)(unsigned short)(hv.z & 0xFFFF); f[5] = (short)(unsigned short)(hv.z >> 16);
      f[6] = (short)(unsigned short)(hv.w & 0xFFFF); f[7] = (short)(unsigned short)(hv.w >> 16);
      afr[s] = f;
    } else {
      uint4 hv = hraw[s];
      uint2 kq = kraw[s];
      float2v f0 = __builtin_amdgcn_cvt_pk_f32_fp8(kq.x, false);
      float2v f1 = __builtin_amdgcn_cvt_pk_f32_fp8(kq.x, true);
      float2v f2 = __builtin_amdgcn_cvt_pk_f32_fp8(kq.y, false);
      float2v f3 = __builtin_amdgcn_cvt_pk_f32_fp8(kq.y, true);
      short8v f;
      f[0] = (short)f2bf(bflo(hv.x) + cyA * f0[0]);
      f[1] = (short)f2bf(bfhi(hv.x) + cyA * f0[1]);
      f[2] = (short)f2bf(bflo(hv.y) + cyA * f1[0]);
      f[3] = (short)f2bf(bfhi(hv.y) + cyA * f1[1]);
      f[4] = (short)f2bf(bflo(hv.z) + cyA * f2[0]);
      f[5] = (short)f2bf(bfhi(hv.z) + cyA * f2[1]);
      f[6] = (short)f2bf(bflo(hv.w) + cyA * f3[0]);
      f[7] = (short)f2bf(bfhi(hv.w) + cyA * f3[1]);
      afr[s] = f;
    }
  }
#pragma unroll
  for (int s = 0; s < 4; ++s) afr[4 + s] = ufr[s];

  float4v acc0 = {0.f, 0.f, 0.f, 0.f};
  float4v acc1 = {0.f, 0.f, 0.f, 0.f};
#pragma unroll
  for (int s = 0; s < 8; ++s) {
    acc0 = __builtin_amdgcn_mfma_f32_16x16x32_bf16(bfr[0][s], afr[s], acc0, 0, 0, 0);
    acc1 = __builtin_amdgcn_mfma_f32_16x16x32_bf16(bfr[1][s], afr[s], acc1, 0, 0, 0);
  }

  if (m < NND) {
#pragma unroll
    for (int t = 0; t < 2; ++t) {
      int n0 = ncol0 + t * 16 + lhi * 4;
      size_t off = (size_t)m * HD + n0;
      float4v acc = t ? acc1 : acc0;
      float4 bo = bo4[t];
      float kv0 = tanhf(acc[0] + bo.x);
      float kv1 = tanhf(acc[1] + bo.y);
      float kv2 = tanhf(acc[2] + bo.z);
      float kv3 = tanhf(acc[3] + bo.w);
      if (stage < 3) {
        unsigned int p8 = __builtin_amdgcn_cvt_pk_fp8_f32(kv0, kv1, 0u, false);
        p8 = __builtin_amdgcn_cvt_pk_fp8_f32(kv2, kv3, p8, true);
        *(unsigned int*)&k8w[off] = p8;
      } else {
        float2v a0 = __builtin_amdgcn_cvt_pk_f32_fp8(q0[t], false);
        float2v a1 = __builtin_amdgcn_cvt_pk_f32_fp8(q0[t], true);
        float2v b0 = __builtin_amdgcn_cvt_pk_f32_fp8(q1[t], false);
        float2v b1 = __builtin_amdgcn_cvt_pk_f32_fp8(q1[t], true);
        float2v c0 = __builtin_amdgcn_cvt_pk_f32_fp8(q2[t], false);
        float2v c1 = __builtin_amdgcn_cvt_pk_f32_fp8(q2[t], true);
        float dh0 = w6 * (a0[0] + 2.f * b0[0] + 2.f * c0[0] + kv0);
        float dh1 = w6 * (a0[1] + 2.f * b0[1] + 2.f * c0[1] + kv1);
        float dh2 = w6 * (a1[0] + 2.f * b1[0] + 2.f * c1[0] + kv2);
        float dh3 = w6 * (a1[1] + 2.f * b1[1] + 2.f * c1[1] + kv3);
        float h0 = bflo(hvp[t].x) + dh0;
        float h1 = bfhi(hvp[t].x) + dh1;
        float h2 = bflo(hvp[t].y) + dh2;
        float h3 = bfhi(hvp[t].y) + dh3;
        uint2 ho;
        ho.x = (unsigned int)f2bf(h0) | ((unsigned int)f2bf(h1) << 16);
        ho.y = (unsigned int)f2bf(h2) | ((unsigned int)f2bf(h3) << 16);
        *(uint2*)&hn[off] = ho;
        unsigned int p8 = __builtin_amdgcn_cvt_pk_fp8_f32(8.0f * dh0, 8.0f * dh1, 0u, false);
        p8 = __builtin_amdgcn_cvt_pk_fp8_f32(8.0f * dh2, 8.0f * dh3, p8, true);
        *(unsigned int*)&dh8[off] = p8;
      }
    }
  }
}

// ---------------- interference (MFMA, swapped operands) ----------------
__global__ __launch_bounds__(256) void k_interf2(
    const unsigned short* __restrict__ hbf, const unsigned short* __restrict__ weffT,
    const float* __restrict__ bint, const float* __restrict__ gint,
    const float* __restrict__ beint,
    const float* __restrict__ alphap, const float* __restrict__ betap,
    const float* __restrict__ phasep,
    unsigned short* __restrict__ h2bf)
{
  __shared__ float red[4][16][2];
  int tid = threadIdx.x;
  int wave = tid >> 6;
  int lane = tid & 63;
  int l15 = lane & 15;
  int lhi = lane >> 4;
  int rowBase = blockIdx.x * 32;
  int ncol0 = wave * 32;

  short8v bfr[2][4];
#pragma unroll
  for (int t = 0; t < 2; ++t) {
    int n = ncol0 + t * 16 + l15;
#pragma unroll
    for (int s = 0; s < 4; ++s)
      bfr[t][s] = *(const short8v*)&weffT[n * 128 + s * 32 + lhi * 8];
  }
  float4 bi4[2], gv4[2], bev4[2];
#pragma unroll
  for (int t = 0; t < 2; ++t) {
    int n0 = ncol0 + t * 16 + lhi * 4;
    bi4[t]  = *(const float4*)&bint[n0];
    gv4[t]  = *(const float4*)&gint[n0];
    bev4[t] = *(const float4*)&beint[n0];
  }

  float al = alphap[0], bt = betap[0], ph = phasep[0];
  float n2 = al*al + bt*bt;
  float p0 = (al*al) / n2, p1 = (bt*bt) / n2;
  float interf = 2.0f * sqrtf(p0 * p1) * cosf(ph);
  float gate = (fabsf(interf) > 0.01f) ? interf : 0.0f;
  float cscale = (p0 > p1) ? 1.0f : cosf(ph);

  for (int rt = 0; rt < 2; ++rt) {
    int mload = rowBase + rt * 16 + l15;
    if (mload >= NND) mload = NND - 1;
    short8v afr[4];
#pragma unroll
    for (int s = 0; s < 4; ++s)
      afr[s] = *(const short8v*)&hbf[(size_t)mload * HD + s * 32 + lhi * 8];

    float4v acc0 = {0.f, 0.f, 0.f, 0.f};
    float4v acc1 = {0.f, 0.f, 0.f, 0.f};
#pragma unroll
    for (int s = 0; s < 4; ++s) {
      acc0 = __builtin_amdgcn_mfma_f32_16x16x32_bf16(bfr[0][s], afr[s], acc0, 0, 0, 0);
      acc1 = __builtin_amdgcn_mfma_f32_16x16x32_bf16(bfr[1][s], afr[s], acc1, 0, 0, 0);
    }

    float z[2][4];
    float s1 = 0.f, s2 = 0.f;
#pragma unroll
    for (int t = 0; t < 2; ++t) {
      float4v acc = t ? acc1 : acc0;
#pragma unroll
      for (int i = 0; i < 4; ++i) {
        float zz = acc[i] + ((const float*)&bi4[t])[i];
        z[t][i] = zz;
        s1 += zz; s2 += zz * zz;
      }
    }
    s1 += __shfl_xor(s1, 16, 64); s2 += __shfl_xor(s2, 16, 64);
    s1 += __shfl_xor(s1, 32, 64); s2 += __shfl_xor(s2, 32, 64);
    if (lhi == 0) { red[wave][l15][0] = s1; red[wave][l15][1] = s2; }
    __syncthreads();
    float S = red[0][l15][0] + red[1][l15][0] + red[2][l15][0] + red[3][l15][0];
    float Q = red[0][l15][1] + red[1][l15][1] + red[2][l15][1] + red[3][l15][1];
    float mean = S * (1.0f / 128.0f);
    float var  = Q * (1.0f / 128.0f) - mean * mean;
    float rs = rsqrtf(var + 1e-5f);

    int m = rowBase + rt * 16 + l15;
    if (m < NND) {
#pragma unroll
      for (int t = 0; t < 2; ++t) {
        size_t off = (size_t)m * HD + ncol0 + t * 16 + lhi * 4;
        uint2 hv = *(const uint2*)&hbf[off];
        float h0 = bflo(hv.x), h1 = bfhi(hv.x), h2 = bflo(hv.y), h3 = bfhi(hv.y);
        float t0 = tanhf((z[t][0]-mean)*rs*((const float*)&gv4[t])[0] + ((const float*)&bev4[t])[0]);
        float t1 = tanhf((z[t][1]-mean)*rs*((const float*)&gv4[t])[1] + ((const float*)&bev4[t])[1]);
        float t2 = tanhf((z[t][2]-mean)*rs*((const float*)&gv4[t])[2] + ((const float*)&bev4[t])[2]);
        float t3 = tanhf((z[t][3]-mean)*rs*((const float*)&gv4[t])[3] + ((const float*)&bev4[t])[3]);
        float o0 = (h0 + gate*t0) * cscale;
        float o1 = (h1 + gate*t1) * cscale;
        float o2 = (h2 + gate*t2) * cscale;
        float o3 = (h3 + gate*t3) * cscale;
        uint2 oo;
        oo.x = (unsigned int)f2bf(o0) | ((unsigned int)f2bf(o1) << 16);
        oo.y = (unsigned int)f2bf(o2) | ((unsigned int)f2bf(o3) << 16);
        *(uint2*)&h2bf[off] = oo;
      }
    }
    __syncthreads();
  }
}

// ---------------- per-graph row-sum (one block per graph, no atomics) ----------------
__global__ __launch_bounds__(256) void k_rowsum(
    const unsigned short* __restrict__ h2bf, const int* __restrict__ rowstart,
    float* __restrict__ sg)
{
  __shared__ float red[8][128];
  int g = blockIdx.x;
  int r0 = rowstart[g], r1 = rowstart[g + 1];
  int colq = threadIdx.x & 31;
  int rowp = threadIdx.x >> 5;
  float a0 = 0.f, a1 = 0.f, a2 = 0.f, a3 = 0.f;
  for (int r = r0 + rowp; r < r1; r += 8) {
    uint2 v = *(const uint2*)&h2bf[(size_t)r * HD + colq * 4];
    a0 += bflo(v.x); a1 += bfhi(v.x); a2 += bflo(v.y); a3 += bfhi(v.y);
  }
  red[rowp][colq * 4 + 0] = a0;
  red[rowp][colq * 4 + 1] = a1;
  red[rowp][colq * 4 + 2] = a2;
  red[rowp][colq * 4 + 3] = a3;
  __syncthreads();
  if (rowp == 0) {
#pragma unroll
    for (int i = 0; i < 4; ++i) {
      int c = colq * 4 + i;
      float s = red[0][c] + red[1][c] + red[2][c] + red[3][c]
              + red[4][c] + red[5][c] + red[6][c] + red[7][c];
      sg[g * HD + c] = s;
    }
  }
}

// ---------------- tiny pool GEMM ----------------
__global__ __launch_bounds__(128) void k_pool(
    const float* __restrict__ sg, const float* __restrict__ Wout,
    const float* __restrict__ bout, const float* __restrict__ cnt,
    float* __restrict__ out)
{
  __shared__ float srow[128];
  int g = blockIdx.x;
  int c = threadIdx.x;
  srow[c] = sg[g * HD + c];
  __syncthreads();
  float s = 0.f;
  for (int k = 0; k < 128; ++k) s += srow[k] * Wout[k * HD + c];
  float cg = cnt[g];
  out[g * HD + c] = (s + cg * bout[c]) / fmaxf(cg, 1.0f);
}

extern "C" void kernel_launch(void* const* d_in, const int* in_sizes, int n_in,
                              void* d_out, int out_size, void* d_ws, size_t ws_size,
                              hipStream_t stream) {
  (void)in_sizes; (void)n_in; (void)out_size; (void)ws_size;
  const float* x     = (const float*)d_in[0];
  const int*   ei    = (const int*)d_in[1];
  const int*   batch = (const int*)d_in[2];
  const float* alpha = (const float*)d_in[3];
  const float* beta  = (const float*)d_in[4];
  const float* phase = (const float*)d_in[5];
  const float* Win   = (const float*)d_in[6];
  const float* bin   = (const float*)d_in[7];
  const float* gin   = (const float*)d_in[8];
  const float* bein  = (const float*)d_in[9];
  const float* Walt  = (const float*)d_in[10];
  const float* balt  = (const float*)d_in[11];
  const float* galt  = (const float*)d_in[12];
  const float* bealt = (const float*)d_in[13];
  const float* Wself = (const float*)d_in[14];
  const float* Wmsg  = (const float*)d_in[15];
  const float* bode  = (const float*)d_in[16];
  const float* Wint  = (const float*)d_in[17];
  const float* bint  = (const float*)d_in[18];
  const float* gint  = (const float*)d_in[19];
  const float* beint = (const float*)d_in[20];
  const float* Wout  = (const float*)d_in[21];
  const float* bout  = (const float*)d_in[22];
  float* out = (float*)d_out;

  const int* esrc = ei;
  const int* edst = ei + NED;

  size_t NH = (size_t)NND * HD;   // 6,400,000
  float* deginv = (float*)d_ws;
  float* cnt    = deginv + NND;
  float* sg     = cnt + NG;
  unsigned short* hA    = (unsigned short*)(sg + NG * HD);
  unsigned short* hB    = hA + NH;
  unsigned short* usav  = hB + NH;
  unsigned short* uT    = usav + NH;
  unsigned short* h2bf  = uT + NH;
  unsigned short* Bt    = h2bf + NH;          // 128*256
  unsigned short* BtIn  = Bt + 128 * 256;     // 2*128*128
  unsigned short* weffT = BtIn + 2 * 128 * 128;  // 128*128
  unsigned short* cs16  = weffT + 128 * 128;     // NED
  unsigned char* k80 = (unsigned char*)(cs16 + NED);
  unsigned char* k81 = k80 + NH;
  unsigned char* k82 = k81 + NH;
  unsigned char* dh8 = k82 + NH;
  int* degi     = (int*)(dh8 + NH);
  int* rowptr   = degi + NND;
  int* cursor   = rowptr + (NND + 4);
  int* rowstart = cursor + NND;

  hipMemsetAsync(degi, 0, NND * sizeof(int), stream);

  k_hist   <<<(NED + 255) / 256, 256, 0, stream>>>(edst, degi);
  k_scan   <<<1, 1024, 0, stream>>>(degi, rowptr, cursor, deginv);
  k_scatter<<<(NED + 255) / 256, 256, 0, stream>>>(esrc, edst, cursor, cs16);
  k_cnt    <<<1, 64, 0, stream>>>(batch, cnt, rowstart);
  k_weffT  <<<64, 256, 0, stream>>>(Wint, weffT);
  k_prepB  <<<128, 256, 0, stream>>>(Wself, Wmsg, Bt);
  k_prepIn <<<128, 256, 0, stream>>>(Win, Walt, BtIn);
  k_init2  <<<(NND + 63) / 64, 256, 0, stream>>>(x, BtIn, bin, gin, bein,
                                                 balt, galt, bealt,
                                                 alpha, beta, hA);

  const float DT = 0.125f;
  int gg = (NND + 15) / 16;       // 3125
  int ob = (NND + MTO - 1) / MTO; // 3125
  unsigned short* hcur = hA;
  unsigned short* hnext = hB;
  for (int step = 0; step < 8; ++step) {
    // stage 0: gather (step0: full bf16 h; else incremental dh8); k0 -> k80
    k_gath2<<<gg, 256, 0, stream>>>(hcur, dh8, usav, uT, rowptr, cs16, deginv,
                                    (step == 0) ? 0 : 1, 0.f);
    k_ode4 <<<ob, 256, 0, stream>>>(hcur, hnext, uT, k80, k80, k80, k81, k82, dh8,
                                    Bt, bode, 0, 0.f);
    // stage 1: gather k80; A = h + dt/2*k80; k1 -> k81
    k_gath2<<<gg, 256, 0, stream>>>(hcur, k80, usav, uT, rowptr, cs16, deginv, 2, 0.5f * DT);
    k_ode4 <<<ob, 256, 0, stream>>>(hcur, hnext, uT, k80, k81, k80, k81, k82, dh8,
                                    Bt, bode, 1, 0.5f * DT);
    // stage 2: gather k81; A = h + dt/2*k81; k2 -> k82
    k_gath2<<<gg, 256, 0, stream>>>(hcur, k81, usav, uT, rowptr, cs16, deginv, 2, 0.5f * DT);
    k_ode4 <<<ob, 256, 0, stream>>>(hcur, hnext, uT, k81, k82, k80, k81, k82, dh8,
                                    Bt, bode, 2, 0.5f * DT);
    // stage 3: gather k82; A = h + dt*k82; h update -> hnext; dh8 emit
    k_gath2<<<gg, 256, 0, stream>>>(hcur, k82, usav, uT, rowptr, cs16, deginv, 2, DT);
    k_ode4 <<<ob, 256, 0, stream>>>(hcur, hnext, uT, k82, k80, k80, k81, k82, dh8,
                                    Bt, bode, 3, DT);
    unsigned short* tmp = hcur; hcur = hnext; hnext = tmp;
  }
  k_interf2<<<(NND + 31) / 32, 256, 0, stream>>>(hcur, weffT, bint, gint, beint,
                                                 alpha, beta, phase, h2bf);
  k_rowsum<<<NG, 256, 0, stream>>>(h2bf, rowstart, sg);
  k_pool  <<<NG, 128, 0, stream>>>(sg, Wout, bout, cnt, out);
}

// Round 14
// 2190.858 us; speedup vs baseline: 1.1044x; 1.1044x over previous
//
#include <hip/hip_runtime.h>
#include <math.h>

#define NND 50000
#define NED 800000
#define HD  128
#define NG  64
#define MT  32

typedef __attribute__((ext_vector_type(8))) short short8v;
typedef __attribute__((ext_vector_type(4))) float float4v;
typedef __attribute__((ext_vector_type(2))) float float2v;

__device__ __forceinline__ float gelu_t(float x) {
  const float c = 0.7978845608028654f;
  float t = tanhf(c * (x + 0.044715f * x * x * x));
  return 0.5f * x * (1.0f + t);
}

__device__ __forceinline__ unsigned short f2bf(float f) {
  unsigned int u = __float_as_uint(f);
  u += 0x7FFFu + ((u >> 16) & 1u);
  return (unsigned short)(u >> 16);
}
__device__ __forceinline__ float bf2f(unsigned short s) {
  return __uint_as_float(((unsigned int)s) << 16);
}
__device__ __forceinline__ float bflo(unsigned int u) { return __uint_as_float(u << 16); }
__device__ __forceinline__ float bfhi(unsigned int u) { return __uint_as_float(u & 0xFFFF0000u); }

// ---------------- CSR build ----------------
__global__ void k_hist(const int* __restrict__ dst, int* __restrict__ degi) {
  int e = blockIdx.x * 256 + threadIdx.x;
  if (e < NED) atomicAdd(&degi[dst[e]], 1);
}

__global__ __launch_bounds__(1024) void k_scan(
    const int* __restrict__ degi, int* __restrict__ rowptr,
    int* __restrict__ cursor, float* __restrict__ deginv) {
  __shared__ int wsum[16];
  int tid = threadIdx.x;
  int lane = tid & 63;
  int wid = tid >> 6;
  int running = 0;
  for (int base = 0; base < NND; base += 1024) {
    int idx = base + tid;
    int v = (idx < NND) ? degi[idx] : 0;
    int s = v;
#pragma unroll
    for (int o = 1; o < 64; o <<= 1) {
      int t = __shfl_up(s, o, 64);
      if (lane >= o) s += t;
    }
    if (lane == 63) wsum[wid] = s;
    __syncthreads();
    if (wid == 0) {
      int ws = (lane < 16) ? wsum[lane] : 0;
#pragma unroll
      for (int o = 1; o < 16; o <<= 1) {
        int t = __shfl_up(ws, o, 64);
        if (lane >= o) ws += t;
      }
      if (lane < 16) wsum[lane] = ws;
    }
    __syncthreads();
    int woff = wid ? wsum[wid - 1] : 0;
    int excl = running + woff + s - v;
    if (idx < NND) {
      rowptr[idx] = excl;
      cursor[idx] = excl;
      deginv[idx] = 1.0f / (float)max(v, 1);
    }
    int tot = wsum[15];
    __syncthreads();
    running += tot;
  }
  if (tid == 0) rowptr[NND] = running;
}

__global__ void k_scatter(const int* __restrict__ src, const int* __restrict__ dst,
                          int* __restrict__ cursor, unsigned short* __restrict__ cs16) {
  int e = blockIdx.x * 256 + threadIdx.x;
  if (e < NED) {
    int d = dst[e];
    int pos = atomicAdd(&cursor[d], 1);
    cs16[pos] = (unsigned short)src[e];
  }
}

// cnt + contiguous row ranges per graph (batch is sorted)
__global__ void k_cnt(const int* __restrict__ batch, float* __restrict__ cnt,
                      int* __restrict__ rowstart) {
  int g = threadIdx.x;
  if (g >= NG) return;
  int lo = 0, hi = NND;
  while (lo < hi) { int mid = (lo + hi) >> 1; if (batch[mid] <= g) lo = mid + 1; else hi = mid; }
  int ub_g = lo;
  int ub_gm1 = 0;
  if (g > 0) {
    lo = 0; hi = NND;
    int v = g - 1;
    while (lo < hi) { int mid = (lo + hi) >> 1; if (batch[mid] <= v) lo = mid + 1; else hi = mid; }
    ub_gm1 = lo;
  }
  cnt[g] = (float)(ub_g - ub_gm1);
  rowstart[g + 1] = ub_g;
  if (g == 0) rowstart[0] = 0;
}

// weffT[n][k] = bf16(Wint[k][n] + Wint[k+128][n])
__global__ void k_weffT(const float* __restrict__ Wint, unsigned short* __restrict__ weffT) {
  int i = blockIdx.x * 256 + threadIdx.x;
  if (i < 128 * 128) {
    int n = i >> 7, k = i & 127;
    weffT[i] = f2bf(Wint[k * 128 + n] + Wint[(k + 128) * 128 + n]);
  }
}

__global__ void k_prepB(const float* __restrict__ Wself, const float* __restrict__ Wmsg,
                        unsigned short* __restrict__ Bt) {
  int i = blockIdx.x * 256 + threadIdx.x;
  if (i < 128 * 256) {
    int n = i >> 8, k = i & 255;
    float w = (k < HD) ? Wself[k * HD + n] : Wmsg[(k - HD) * HD + n];
    Bt[i] = f2bf(w);
  }
}

__global__ void k_prepIn(const float* __restrict__ Win, const float* __restrict__ Walt,
                         unsigned short* __restrict__ BtIn) {
  int i = blockIdx.x * 256 + threadIdx.x;
  if (i < 2 * 128 * 128) {
    int p = i >> 14; int rem = i & 16383; int n = rem >> 7; int k = rem & 127;
    const float* W = p ? Walt : Win;
    BtIn[i] = f2bf(W[k * 128 + n]);
  }
}

// ---------------- init (MFMA): writes hbf only ----------------
__global__ __launch_bounds__(256) void k_init2(
    const float* __restrict__ x, const unsigned short* __restrict__ BtIn,
    const float* __restrict__ bin, const float* __restrict__ gin, const float* __restrict__ bein,
    const float* __restrict__ balt, const float* __restrict__ galt, const float* __restrict__ bealt,
    const float* __restrict__ alphap, const float* __restrict__ betap,
    unsigned short* __restrict__ hbf)
{
  __shared__ float red[4][16][2];
  __shared__ unsigned short gtile[2][16][64];
  int tid = threadIdx.x;
  int wave = tid >> 6;
  int lane = tid & 63;
  int l15 = lane & 15;
  int lhi = lane >> 4;
  int path = wave >> 1;
  int colBase = (wave & 1) * 64;
  int rowBase = blockIdx.x * 64;

  const unsigned short* Bp = BtIn + path * 128 * 128;
  short8v bfr[4][4];
#pragma unroll
  for (int t = 0; t < 4; ++t) {
    int n = colBase + t * 16 + l15;
#pragma unroll
    for (int s = 0; s < 4; ++s)
      bfr[t][s] = *(const short8v*)&Bp[n * 128 + s * 32 + lhi * 8];
  }

  const float* bvp = path ? balt : bin;
  const float* gp  = path ? galt : gin;
  const float* bep = path ? bealt : bein;
  float bv[4], gw[4], bew[4];
#pragma unroll
  for (int t = 0; t < 4; ++t) {
    int col = colBase + t * 16 + l15;
    bv[t] = bvp[col]; gw[t] = gp[col]; bew[t] = bep[col];
  }

  float al = alphap[0], btv = betap[0];
  float nrm = sqrtf(al * al + btv * btv);
  float w0 = fabsf(al) / nrm, w1 = fabsf(btv) / nrm;

  for (int rt = 0; rt < 4; ++rt) {
    int arow = rowBase + rt * 16 + l15; if (arow >= NND) arow = NND - 1;
    short8v afr[4];
#pragma unroll
    for (int s = 0; s < 4; ++s) {
      float4 xa = *(const float4*)&x[(size_t)arow * HD + s * 32 + lhi * 8];
      float4 xb = *(const float4*)&x[(size_t)arow * HD + s * 32 + lhi * 8 + 4];
      short8v f;
      f[0] = (short)f2bf(xa.x); f[1] = (short)f2bf(xa.y);
      f[2] = (short)f2bf(xa.z); f[3] = (short)f2bf(xa.w);
      f[4] = (short)f2bf(xb.x); f[5] = (short)f2bf(xb.y);
      f[6] = (short)f2bf(xb.z); f[7] = (short)f2bf(xb.w);
      afr[s] = f;
    }

    float4v acc[4];
#pragma unroll
    for (int t = 0; t < 4; ++t) acc[t] = (float4v){0.f, 0.f, 0.f, 0.f};
#pragma unroll
    for (int s = 0; s < 4; ++s) {
#pragma unroll
      for (int t = 0; t < 4; ++t)
        acc[t] = __builtin_amdgcn_mfma_f32_16x16x32_bf16(afr[s], bfr[t][s], acc[t], 0, 0, 0);
    }

    float z[4][4];
    float psum[4], psq[4];
#pragma unroll
    for (int r = 0; r < 4; ++r) {
      float s1 = 0.f, s2 = 0.f;
#pragma unroll
      for (int t = 0; t < 4; ++t) {
        float zz = acc[t][r] + bv[t];
        z[r][t] = zz;
        s1 += zz; s2 += zz * zz;
      }
#pragma unroll
      for (int m = 1; m < 16; m <<= 1) {
        s1 += __shfl_xor(s1, m, 16);
        s2 += __shfl_xor(s2, m, 16);
      }
      psum[r] = s1; psq[r] = s2;
    }
    if (l15 == 0) {
#pragma unroll
      for (int r = 0; r < 4; ++r) {
        red[wave][lhi * 4 + r][0] = psum[r];
        red[wave][lhi * 4 + r][1] = psq[r];
      }
    }
    __syncthreads();

    int pw = wave ^ 1;
    float gval[4][4];
#pragma unroll
    for (int r = 0; r < 4; ++r) {
      int rowl = lhi * 4 + r;
      float S = psum[r] + red[pw][rowl][0];
      float Q = psq[r]  + red[pw][rowl][1];
      float mean = S * (1.0f / 128.0f);
      float var  = Q * (1.0f / 128.0f) - mean * mean;
      float rs = rsqrtf(var + 1e-5f);
#pragma unroll
      for (int t = 0; t < 4; ++t)
        gval[r][t] = gelu_t((z[r][t] - mean) * rs * gw[t] + bew[t]);
    }

    if (path == 1) {
#pragma unroll
      for (int r = 0; r < 4; ++r)
#pragma unroll
        for (int t = 0; t < 4; ++t)
          gtile[wave & 1][lhi * 4 + r][t * 16 + l15] = f2bf(gval[r][t]);
    }
    __syncthreads();

    if (path == 0) {
#pragma unroll
      for (int r = 0; r < 4; ++r) {
        int m = rowBase + rt * 16 + lhi * 4 + r;
        if (m < NND) {
#pragma unroll
          for (int t = 0; t < 4; ++t) {
            float g1 = bf2f(gtile[wave & 1][lhi * 4 + r][t * 16 + l15]);
            float hv = w0 * gval[r][t] + w1 * g1;
            hbf[(size_t)m * HD + colBase + t * 16 + l15] = f2bf(hv);
          }
        }
      }
    }
    __syncthreads();
  }
}

// ---------------- gather kernel ----------------
// mode 0: u = meanagg(hbf); usav = u     (step-0 stage-0)
// mode 1: usav += meanagg(dh8)/8; u = usav  (stage-0 later steps)
// mode 2: u = usav + cu*meanagg(t8)         (stages 1-3)
__global__ __launch_bounds__(256) void k_gath2(
    const unsigned short* __restrict__ hbf,
    const unsigned char*  __restrict__ t8,
    unsigned short* __restrict__ usav,
    unsigned short* __restrict__ uT,
    const int* __restrict__ rowptr,
    const unsigned short* __restrict__ cs16,
    const float* __restrict__ deginv,
    int mode, float cu)
{
  int tid = threadIdx.x;
  int l16 = tid & 15;
  int grp = tid >> 4;
  int node = blockIdx.x * 16 + grp;
  if (node >= NND) return;
  int e0 = rowptr[node], e1 = rowptr[node + 1];
  float a0=0,a1=0,a2=0,a3=0,a4=0,a5=0,a6=0,a7=0;

  if (mode == 0) {
    for (int eb = e0; eb < e1; eb += 16) {
      int rem = e1 - eb;
      int ia = eb + l16; if (ia > e1 - 1) ia = e1 - 1;
      int my = cs16[ia];
      int n16 = (rem < 16) ? rem : 16;
#pragma unroll
      for (int j = 0; j < 16; ++j) {
        if (j < n16) {
          int s = __shfl(my, j, 16);
          uint4 v = *(const uint4*)&hbf[(size_t)s * HD + l16 * 8];
          a0 += bflo(v.x); a1 += bfhi(v.x); a2 += bflo(v.y); a3 += bfhi(v.y);
          a4 += bflo(v.z); a5 += bfhi(v.z); a6 += bflo(v.w); a7 += bfhi(v.w);
        }
      }
    }
  } else {
    for (int eb = e0; eb < e1; eb += 16) {
      int rem = e1 - eb;
      int ia = eb + l16; if (ia > e1 - 1) ia = e1 - 1;
      int my = cs16[ia];
      int n16 = (rem < 16) ? rem : 16;
      uint2 v[16];
#pragma unroll
      for (int j = 0; j < 16; ++j) {
        if (j < n16) {
          int s = __shfl(my, j, 16);
          v[j] = *(const uint2*)&t8[(size_t)s * HD + l16 * 8];
        }
      }
#pragma unroll
      for (int j = 0; j < 16; ++j) {
        if (j < n16) {
          float2v f0 = __builtin_amdgcn_cvt_pk_f32_fp8(v[j].x, false);
          float2v f1 = __builtin_amdgcn_cvt_pk_f32_fp8(v[j].x, true);
          float2v f2 = __builtin_amdgcn_cvt_pk_f32_fp8(v[j].y, false);
          float2v f3 = __builtin_amdgcn_cvt_pk_f32_fp8(v[j].y, true);
          a0 += f0[0]; a1 += f0[1]; a2 += f1[0]; a3 += f1[1];
          a4 += f2[0]; a5 += f2[1]; a6 += f3[0]; a7 += f3[1];
        }
      }
    }
  }

  float sc = deginv[node] * ((mode == 0) ? 1.0f : ((mode == 1) ? 0.125f : cu));
  size_t base = (size_t)node * HD + l16 * 8;
  float u0,u1,u2,u3,u4,u5,u6,u7;
  if (mode == 0) {
    u0=a0*sc; u1=a1*sc; u2=a2*sc; u3=a3*sc; u4=a4*sc; u5=a5*sc; u6=a6*sc; u7=a7*sc;
  } else {
    uint4 us = *(const uint4*)&usav[base];
    u0 = bflo(us.x) + a0*sc; u1 = bfhi(us.x) + a1*sc;
    u2 = bflo(us.y) + a2*sc; u3 = bfhi(us.y) + a3*sc;
    u4 = bflo(us.z) + a4*sc; u5 = bfhi(us.z) + a5*sc;
    u6 = bflo(us.w) + a6*sc; u7 = bfhi(us.w) + a7*sc;
  }
  uint4 o;
  o.x = (unsigned int)f2bf(u0) | ((unsigned int)f2bf(u1) << 16);
  o.y = (unsigned int)f2bf(u2) | ((unsigned int)f2bf(u3) << 16);
  o.z = (unsigned int)f2bf(u4) | ((unsigned int)f2bf(u5) << 16);
  o.w = (unsigned int)f2bf(u6) | ((unsigned int)f2bf(u7) << 16);
  if (mode <= 1) *(uint4*)&usav[base] = o;
  *(uint4*)&uT[base] = o;
}

// ---------------- ODE GEMM (MT=32, hoisted stage-3 preloads) ----------------
__global__ __launch_bounds__(256) void k_ode3(
    const unsigned short* __restrict__ hc,
    unsigned short* __restrict__ hn,
    const unsigned short* __restrict__ uT,
    const unsigned char* __restrict__ k8A,
    unsigned char* __restrict__ k8w,
    const unsigned char* __restrict__ k8r0,
    const unsigned char* __restrict__ k8r1,
    const unsigned char* __restrict__ k8r2,
    unsigned char* __restrict__ dh8,
    const unsigned short* __restrict__ Bt, const float* __restrict__ bode,
    int stage, float cyA)
{
  int tid = threadIdx.x;
  int wave = tid >> 6;
  int lane = tid & 63;
  int l15 = lane & 15;
  int lhi = lane >> 4;
  int rowBase = blockIdx.x * MT;
  int ncol0 = wave * 32;

  const float DT = 0.125f;
  const float w6 = DT / 6.0f;

  short8v bfr[2][8];
#pragma unroll
  for (int t = 0; t < 2; ++t) {
    int n = ncol0 + t * 16 + l15;
#pragma unroll
    for (int s = 0; s < 8; ++s) {
      bfr[t][s] = *(const short8v*)&Bt[n * 256 + s * 32 + lhi * 8];
    }
  }
  float4 bo4[2];
  bo4[0] = *(const float4*)&bode[ncol0 + lhi * 4];
  bo4[1] = *(const float4*)&bode[ncol0 + 16 + lhi * 4];

#pragma unroll
  for (int rt = 0; rt < MT / 16; ++rt) {
    int mload = rowBase + rt * 16 + l15;
    if (mload >= NND) mload = NND - 1;

    // hoisted stage-3 epilogue preloads (fly under A-build + MFMA)
    unsigned int q0[2], q1[2], q2[2];
    uint2 hvp[2];
    if (stage == 3) {
#pragma unroll
      for (int t = 0; t < 2; ++t) {
        size_t eoff = (size_t)mload * HD + ncol0 + t * 16 + lhi * 4;
        q0[t] = *(const unsigned int*)&k8r0[eoff];
        q1[t] = *(const unsigned int*)&k8r1[eoff];
        q2[t] = *(const unsigned int*)&k8r2[eoff];
        hvp[t] = *(const uint2*)&hc[eoff];
      }
    }

    short8v afr[8];
#pragma unroll
    for (int s = 0; s < 4; ++s) {
      size_t base = (size_t)mload * HD + s * 32 + lhi * 8;
      if (stage == 0) {
        afr[s] = *(const short8v*)&hc[base];
      } else {
        uint4 hv = *(const uint4*)&hc[base];
        uint2 kq = *(const uint2*)&k8A[base];
        float2v f0 = __builtin_amdgcn_cvt_pk_f32_fp8(kq.x, false);
        float2v f1 = __builtin_amdgcn_cvt_pk_f32_fp8(kq.x, true);
        float2v f2 = __builtin_amdgcn_cvt_pk_f32_fp8(kq.y, false);
        float2v f3 = __builtin_amdgcn_cvt_pk_f32_fp8(kq.y, true);
        short8v f;
        f[0] = (short)f2bf(bflo(hv.x) + cyA * f0[0]);
        f[1] = (short)f2bf(bfhi(hv.x) + cyA * f0[1]);
        f[2] = (short)f2bf(bflo(hv.y) + cyA * f1[0]);
        f[3] = (short)f2bf(bfhi(hv.y) + cyA * f1[1]);
        f[4] = (short)f2bf(bflo(hv.z) + cyA * f2[0]);
        f[5] = (short)f2bf(bfhi(hv.z) + cyA * f2[1]);
        f[6] = (short)f2bf(bflo(hv.w) + cyA * f3[0]);
        f[7] = (short)f2bf(bfhi(hv.w) + cyA * f3[1]);
        afr[s] = f;
      }
    }
#pragma unroll
    for (int s = 0; s < 4; ++s)
      afr[4 + s] = *(const short8v*)&uT[(size_t)mload * HD + s * 32 + lhi * 8];

    float4v acc0 = {0.f, 0.f, 0.f, 0.f};
    float4v acc1 = {0.f, 0.f, 0.f, 0.f};
#pragma unroll
    for (int s = 0; s < 8; ++s) {
      acc0 = __builtin_amdgcn_mfma_f32_16x16x32_bf16(bfr[0][s], afr[s], acc0, 0, 0, 0);
      acc1 = __builtin_amdgcn_mfma_f32_16x16x32_bf16(bfr[1][s], afr[s], acc1, 0, 0, 0);
    }

    int m = rowBase + rt * 16 + l15;
    if (m < NND) {
#pragma unroll
      for (int t = 0; t < 2; ++t) {
        int n0 = ncol0 + t * 16 + lhi * 4;
        size_t off = (size_t)m * HD + n0;
        float4v acc = t ? acc1 : acc0;
        float4 bo = bo4[t];
        float kv0 = tanhf(acc[0] + bo.x);
        float kv1 = tanhf(acc[1] + bo.y);
        float kv2 = tanhf(acc[2] + bo.z);
        float kv3 = tanhf(acc[3] + bo.w);
        if (stage < 3) {
          unsigned int p8 = __builtin_amdgcn_cvt_pk_fp8_f32(kv0, kv1, 0u, false);
          p8 = __builtin_amdgcn_cvt_pk_fp8_f32(kv2, kv3, p8, true);
          *(unsigned int*)&k8w[off] = p8;
        } else {
          float2v a0 = __builtin_amdgcn_cvt_pk_f32_fp8(q0[t], false);
          float2v a1 = __builtin_amdgcn_cvt_pk_f32_fp8(q0[t], true);
          float2v b0 = __builtin_amdgcn_cvt_pk_f32_fp8(q1[t], false);
          float2v b1 = __builtin_amdgcn_cvt_pk_f32_fp8(q1[t], true);
          float2v c0 = __builtin_amdgcn_cvt_pk_f32_fp8(q2[t], false);
          float2v c1 = __builtin_amdgcn_cvt_pk_f32_fp8(q2[t], true);
          float dh0 = w6 * (a0[0] + 2.f * b0[0] + 2.f * c0[0] + kv0);
          float dh1 = w6 * (a0[1] + 2.f * b0[1] + 2.f * c0[1] + kv1);
          float dh2 = w6 * (a1[0] + 2.f * b1[0] + 2.f * c1[0] + kv2);
          float dh3 = w6 * (a1[1] + 2.f * b1[1] + 2.f * c1[1] + kv3);
          float h0 = bflo(hvp[t].x) + dh0;
          float h1 = bfhi(hvp[t].x) + dh1;
          float h2 = bflo(hvp[t].y) + dh2;
          float h3 = bfhi(hvp[t].y) + dh3;
          uint2 ho;
          ho.x = (unsigned int)f2bf(h0) | ((unsigned int)f2bf(h1) << 16);
          ho.y = (unsigned int)f2bf(h2) | ((unsigned int)f2bf(h3) << 16);
          *(uint2*)&hn[off] = ho;
          unsigned int p8 = __builtin_amdgcn_cvt_pk_fp8_f32(8.0f * dh0, 8.0f * dh1, 0u, false);
          p8 = __builtin_amdgcn_cvt_pk_fp8_f32(8.0f * dh2, 8.0f * dh3, p8, true);
          *(unsigned int*)&dh8[off] = p8;
        }
      }
    }
  }
}

// ---------------- interference (MFMA, swapped operands) ----------------
__global__ __launch_bounds__(256) void k_interf2(
    const unsigned short* __restrict__ hbf, const unsigned short* __restrict__ weffT,
    const float* __restrict__ bint, const float* __restrict__ gint,
    const float* __restrict__ beint,
    const float* __restrict__ alphap, const float* __restrict__ betap,
    const float* __restrict__ phasep,
    unsigned short* __restrict__ h2bf)
{
  __shared__ float red[4][16][2];
  int tid = threadIdx.x;
  int wave = tid >> 6;
  int lane = tid & 63;
  int l15 = lane & 15;
  int lhi = lane >> 4;
  int rowBase = blockIdx.x * 32;
  int ncol0 = wave * 32;

  short8v bfr[2][4];
#pragma unroll
  for (int t = 0; t < 2; ++t) {
    int n = ncol0 + t * 16 + l15;
#pragma unroll
    for (int s = 0; s < 4; ++s)
      bfr[t][s] = *(const short8v*)&weffT[n * 128 + s * 32 + lhi * 8];
  }
  float4 bi4[2], gv4[2], bev4[2];
#pragma unroll
  for (int t = 0; t < 2; ++t) {
    int n0 = ncol0 + t * 16 + lhi * 4;
    bi4[t]  = *(const float4*)&bint[n0];
    gv4[t]  = *(const float4*)&gint[n0];
    bev4[t] = *(const float4*)&beint[n0];
  }

  float al = alphap[0], bt = betap[0], ph = phasep[0];
  float n2 = al*al + bt*bt;
  float p0 = (al*al) / n2, p1 = (bt*bt) / n2;
  float interf = 2.0f * sqrtf(p0 * p1) * cosf(ph);
  float gate = (fabsf(interf) > 0.01f) ? interf : 0.0f;
  float cscale = (p0 > p1) ? 1.0f : cosf(ph);

  for (int rt = 0; rt < 2; ++rt) {
    int mload = rowBase + rt * 16 + l15;
    if (mload >= NND) mload = NND - 1;
    short8v afr[4];
#pragma unroll
    for (int s = 0; s < 4; ++s)
      afr[s] = *(const short8v*)&hbf[(size_t)mload * HD + s * 32 + lhi * 8];

    float4v acc0 = {0.f, 0.f, 0.f, 0.f};
    float4v acc1 = {0.f, 0.f, 0.f, 0.f};
#pragma unroll
    for (int s = 0; s < 4; ++s) {
      acc0 = __builtin_amdgcn_mfma_f32_16x16x32_bf16(bfr[0][s], afr[s], acc0, 0, 0, 0);
      acc1 = __builtin_amdgcn_mfma_f32_16x16x32_bf16(bfr[1][s], afr[s], acc1, 0, 0, 0);
    }

    float z[2][4];
    float s1 = 0.f, s2 = 0.f;
#pragma unroll
    for (int t = 0; t < 2; ++t) {
      float4v acc = t ? acc1 : acc0;
#pragma unroll
      for (int i = 0; i < 4; ++i) {
        float zz = acc[i] + ((const float*)&bi4[t])[i];
        z[t][i] = zz;
        s1 += zz; s2 += zz * zz;
      }
    }
    s1 += __shfl_xor(s1, 16, 64); s2 += __shfl_xor(s2, 16, 64);
    s1 += __shfl_xor(s1, 32, 64); s2 += __shfl_xor(s2, 32, 64);
    if (lhi == 0) { red[wave][l15][0] = s1; red[wave][l15][1] = s2; }
    __syncthreads();
    float S = red[0][l15][0] + red[1][l15][0] + red[2][l15][0] + red[3][l15][0];
    float Q = red[0][l15][1] + red[1][l15][1] + red[2][l15][1] + red[3][l15][1];
    float mean = S * (1.0f / 128.0f);
    float var  = Q * (1.0f / 128.0f) - mean * mean;
    float rs = rsqrtf(var + 1e-5f);

    int m = rowBase + rt * 16 + l15;
    if (m < NND) {
#pragma unroll
      for (int t = 0; t < 2; ++t) {
        size_t off = (size_t)m * HD + ncol0 + t * 16 + lhi * 4;
        uint2 hv = *(const uint2*)&hbf[off];
        float h0 = bflo(hv.x), h1 = bfhi(hv.x), h2 = bflo(hv.y), h3 = bfhi(hv.y);
        float t0 = tanhf((z[t][0]-mean)*rs*((const float*)&gv4[t])[0] + ((const float*)&bev4[t])[0]);
        float t1 = tanhf((z[t][1]-mean)*rs*((const float*)&gv4[t])[1] + ((const float*)&bev4[t])[1]);
        float t2 = tanhf((z[t][2]-mean)*rs*((const float*)&gv4[t])[2] + ((const float*)&bev4[t])[2]);
        float t3 = tanhf((z[t][3]-mean)*rs*((const float*)&gv4[t])[3] + ((const float*)&bev4[t])[3]);
        float o0 = (h0 + gate*t0) * cscale;
        float o1 = (h1 + gate*t1) * cscale;
        float o2 = (h2 + gate*t2) * cscale;
        float o3 = (h3 + gate*t3) * cscale;
        uint2 oo;
        oo.x = (unsigned int)f2bf(o0) | ((unsigned int)f2bf(o1) << 16);
        oo.y = (unsigned int)f2bf(o2) | ((unsigned int)f2bf(o3) << 16);
        *(uint2*)&h2bf[off] = oo;
      }
    }
    __syncthreads();
  }
}

// ---------------- per-graph row-sum (one block per graph, no atomics) ----------------
__global__ __launch_bounds__(256) void k_rowsum(
    const unsigned short* __restrict__ h2bf, const int* __restrict__ rowstart,
    float* __restrict__ sg)
{
  __shared__ float red[8][128];
  int g = blockIdx.x;
  int r0 = rowstart[g], r1 = rowstart[g + 1];
  int colq = threadIdx.x & 31;
  int rowp = threadIdx.x >> 5;
  float a0 = 0.f, a1 = 0.f, a2 = 0.f, a3 = 0.f;
  for (int r = r0 + rowp; r < r1; r += 8) {
    uint2 v = *(const uint2*)&h2bf[(size_t)r * HD + colq * 4];
    a0 += bflo(v.x); a1 += bfhi(v.x); a2 += bflo(v.y); a3 += bfhi(v.y);
  }
  red[rowp][colq * 4 + 0] = a0;
  red[rowp][colq * 4 + 1] = a1;
  red[rowp][colq * 4 + 2] = a2;
  red[rowp][colq * 4 + 3] = a3;
  __syncthreads();
  if (rowp == 0) {
#pragma unroll
    for (int i = 0; i < 4; ++i) {
      int c = colq * 4 + i;
      float s = red[0][c] + red[1][c] + red[2][c] + red[3][c]
              + red[4][c] + red[5][c] + red[6][c] + red[7][c];
      sg[g * HD + c] = s;
    }
  }
}

// ---------------- tiny pool GEMM ----------------
__global__ __launch_bounds__(128) void k_pool(
    const float* __restrict__ sg, const float* __restrict__ Wout,
    const float* __restrict__ bout, const float* __restrict__ cnt,
    float* __restrict__ out)
{
  __shared__ float srow[128];
  int g = blockIdx.x;
  int c = threadIdx.x;
  srow[c] = sg[g * HD + c];
  __syncthreads();
  float s = 0.f;
  for (int k = 0; k < 128; ++k) s += srow[k] * Wout[k * HD + c];
  float cg = cnt[g];
  out[g * HD + c] = (s + cg * bout[c]) / fmaxf(cg, 1.0f);
}

extern "C" void kernel_launch(void* const* d_in, const int* in_sizes, int n_in,
                              void* d_out, int out_size, void* d_ws, size_t ws_size,
                              hipStream_t stream) {
  (void)in_sizes; (void)n_in; (void)out_size; (void)ws_size;
  const float* x     = (const float*)d_in[0];
  const int*   ei    = (const int*)d_in[1];
  const int*   batch = (const int*)d_in[2];
  const float* alpha = (const float*)d_in[3];
  const float* beta  = (const float*)d_in[4];
  const float* phase = (const float*)d_in[5];
  const float* Win   = (const float*)d_in[6];
  const float* bin   = (const float*)d_in[7];
  const float* gin   = (const float*)d_in[8];
  const float* bein  = (const float*)d_in[9];
  const float* Walt  = (const float*)d_in[10];
  const float* balt  = (const float*)d_in[11];
  const float* galt  = (const float*)d_in[12];
  const float* bealt = (const float*)d_in[13];
  const float* Wself = (const float*)d_in[14];
  const float* Wmsg  = (const float*)d_in[15];
  const float* bode  = (const float*)d_in[16];
  const float* Wint  = (const float*)d_in[17];
  const float* bint  = (const float*)d_in[18];
  const float* gint  = (const float*)d_in[19];
  const float* beint = (const float*)d_in[20];
  const float* Wout  = (const float*)d_in[21];
  const float* bout  = (const float*)d_in[22];
  float* out = (float*)d_out;

  const int* esrc = ei;
  const int* edst = ei + NED;

  size_t NH = (size_t)NND * HD;   // 6,400,000
  float* deginv = (float*)d_ws;
  float* cnt    = deginv + NND;
  float* sg     = cnt + NG;
  unsigned short* hA    = (unsigned short*)(sg + NG * HD);
  unsigned short* hB    = hA + NH;
  unsigned short* usav  = hB + NH;
  unsigned short* uT    = usav + NH;
  unsigned short* h2bf  = uT + NH;
  unsigned short* Bt    = h2bf + NH;          // 128*256
  unsigned short* BtIn  = Bt + 128 * 256;     // 2*128*128
  unsigned short* weffT = BtIn + 2 * 128 * 128;  // 128*128
  unsigned short* cs16  = weffT + 128 * 128;     // NED
  unsigned char* k80 = (unsigned char*)(cs16 + NED);
  unsigned char* k81 = k80 + NH;
  unsigned char* k82 = k81 + NH;
  unsigned char* dh8 = k82 + NH;
  int* degi     = (int*)(dh8 + NH);
  int* rowptr   = degi + NND;
  int* cursor   = rowptr + (NND + 4);
  int* rowstart = cursor + NND;

  hipMemsetAsync(degi, 0, NND * sizeof(int), stream);

  k_hist   <<<(NED + 255) / 256, 256, 0, stream>>>(edst, degi);
  k_scan   <<<1, 1024, 0, stream>>>(degi, rowptr, cursor, deginv);
  k_scatter<<<(NED + 255) / 256, 256, 0, stream>>>(esrc, edst, cursor, cs16);
  k_cnt    <<<1, 64, 0, stream>>>(batch, cnt, rowstart);
  k_weffT  <<<64, 256, 0, stream>>>(Wint, weffT);
  k_prepB  <<<128, 256, 0, stream>>>(Wself, Wmsg, Bt);
  k_prepIn <<<128, 256, 0, stream>>>(Win, Walt, BtIn);
  k_init2  <<<(NND + 63) / 64, 256, 0, stream>>>(x, BtIn, bin, gin, bein,
                                                 balt, galt, bealt,
                                                 alpha, beta, hA);

  const float DT = 0.125f;
  int gg = (NND + 15) / 16;     // 3125
  int ob = (NND + MT - 1) / MT; // 1563
  unsigned short* hcur = hA;
  unsigned short* hnext = hB;
  for (int step = 0; step < 8; ++step) {
    // stage 0: gather (step0: full bf16 h; else incremental dh8); k0 -> k80
    k_gath2<<<gg, 256, 0, stream>>>(hcur, dh8, usav, uT, rowptr, cs16, deginv,
                                    (step == 0) ? 0 : 1, 0.f);
    k_ode3 <<<ob, 256, 0, stream>>>(hcur, hnext, uT, k80, k80, k80, k81, k82, dh8,
                                    Bt, bode, 0, 0.f);
    // stage 1: gather k80; A = h + dt/2*k80; k1 -> k81
    k_gath2<<<gg, 256, 0, stream>>>(hcur, k80, usav, uT, rowptr, cs16, deginv, 2, 0.5f * DT);
    k_ode3 <<<ob, 256, 0, stream>>>(hcur, hnext, uT, k80, k81, k80, k81, k82, dh8,
                                    Bt, bode, 1, 0.5f * DT);
    // stage 2: gather k81; A = h + dt/2*k81; k2 -> k82
    k_gath2<<<gg, 256, 0, stream>>>(hcur, k81, usav, uT, rowptr, cs16, deginv, 2, 0.5f * DT);
    k_ode3 <<<ob, 256, 0, stream>>>(hcur, hnext, uT, k81, k82, k80, k81, k82, dh8,
                                    Bt, bode, 2, 0.5f * DT);
    // stage 3: gather k82; A = h + dt*k82; h update -> hnext; dh8 emit
    k_gath2<<<gg, 256, 0, stream>>>(hcur, k82, usav, uT, rowptr, cs16, deginv, 2, DT);
    k_ode3 <<<ob, 256, 0, stream>>>(hcur, hnext, uT, k82, k80, k80, k81, k82, dh8,
                                    Bt, bode, 3, DT);
    unsigned short* tmp = hcur; hcur = hnext; hnext = tmp;
  }
  k_interf2<<<(NND + 31) / 32, 256, 0, stream>>>(hcur, weffT, bint, gint, beint,
                                                 alpha, beta, phase, h2bf);
  k_rowsum<<<NG, 256, 0, stream>>>(h2bf, rowstart, sg);
  k_pool  <<<NG, 128, 0, stream>>>(sg, Wout, bout, cnt, out);
}

// Round 15
// 2065.244 us; speedup vs baseline: 1.1715x; 1.0608x over previous
//
#include <hip/hip_runtime.h>
#include <math.h>

#define NND 50000
#define NED 800000
#define HD  128
#define NG  64
#define MT  64

typedef __attribute__((ext_vector_type(8))) short short8v;
typedef __attribute__((ext_vector_type(4))) float float4v;
typedef __attribute__((ext_vector_type(2))) float float2v;

__device__ __forceinline__ float gelu_t(float x) {
  const float c = 0.7978845608028654f;
  float t = tanhf(c * (x + 0.044715f * x * x * x));
  return 0.5f * x * (1.0f + t);
}

__device__ __forceinline__ unsigned short f2bf(float f) {
  unsigned int u = __float_as_uint(f);
  u += 0x7FFFu + ((u >> 16) & 1u);
  return (unsigned short)(u >> 16);
}
__device__ __forceinline__ float bf2f(unsigned short s) {
  return __uint_as_float(((unsigned int)s) << 16);
}
__device__ __forceinline__ float bflo(unsigned int u) { return __uint_as_float(u << 16); }
__device__ __forceinline__ float bfhi(unsigned int u) { return __uint_as_float(u & 0xFFFF0000u); }

// ---------------- CSR build ----------------
__global__ void k_hist(const int* __restrict__ dst, int* __restrict__ degi) {
  int e = blockIdx.x * 256 + threadIdx.x;
  if (e < NED) atomicAdd(&degi[dst[e]], 1);
}

__global__ __launch_bounds__(1024) void k_scan(
    const int* __restrict__ degi, int* __restrict__ rowptr,
    int* __restrict__ cursor, float* __restrict__ deginv) {
  __shared__ int wsum[16];
  int tid = threadIdx.x;
  int lane = tid & 63;
  int wid = tid >> 6;
  int running = 0;
  for (int base = 0; base < NND; base += 1024) {
    int idx = base + tid;
    int v = (idx < NND) ? degi[idx] : 0;
    int s = v;
#pragma unroll
    for (int o = 1; o < 64; o <<= 1) {
      int t = __shfl_up(s, o, 64);
      if (lane >= o) s += t;
    }
    if (lane == 63) wsum[wid] = s;
    __syncthreads();
    if (wid == 0) {
      int ws = (lane < 16) ? wsum[lane] : 0;
#pragma unroll
      for (int o = 1; o < 16; o <<= 1) {
        int t = __shfl_up(ws, o, 64);
        if (lane >= o) ws += t;
      }
      if (lane < 16) wsum[lane] = ws;
    }
    __syncthreads();
    int woff = wid ? wsum[wid - 1] : 0;
    int excl = running + woff + s - v;
    if (idx < NND) {
      rowptr[idx] = excl;
      cursor[idx] = excl;
      deginv[idx] = 1.0f / (float)max(v, 1);
    }
    int tot = wsum[15];
    __syncthreads();
    running += tot;
  }
  if (tid == 0) rowptr[NND] = running;
}

__global__ void k_scatter(const int* __restrict__ src, const int* __restrict__ dst,
                          int* __restrict__ cursor, unsigned short* __restrict__ cs16) {
  int e = blockIdx.x * 256 + threadIdx.x;
  if (e < NED) {
    int d = dst[e];
    int pos = atomicAdd(&cursor[d], 1);
    cs16[pos] = (unsigned short)src[e];
  }
}

// cnt + contiguous row ranges per graph (batch is sorted)
__global__ void k_cnt(const int* __restrict__ batch, float* __restrict__ cnt,
                      int* __restrict__ rowstart) {
  int g = threadIdx.x;
  if (g >= NG) return;
  int lo = 0, hi = NND;
  while (lo < hi) { int mid = (lo + hi) >> 1; if (batch[mid] <= g) lo = mid + 1; else hi = mid; }
  int ub_g = lo;
  int ub_gm1 = 0;
  if (g > 0) {
    lo = 0; hi = NND;
    int v = g - 1;
    while (lo < hi) { int mid = (lo + hi) >> 1; if (batch[mid] <= v) lo = mid + 1; else hi = mid; }
    ub_gm1 = lo;
  }
  cnt[g] = (float)(ub_g - ub_gm1);
  rowstart[g + 1] = ub_g;
  if (g == 0) rowstart[0] = 0;
}

// weffT[n][k] = bf16(Wint[k][n] + Wint[k+128][n])
__global__ void k_weffT(const float* __restrict__ Wint, unsigned short* __restrict__ weffT) {
  int i = blockIdx.x * 256 + threadIdx.x;
  if (i < 128 * 128) {
    int n = i >> 7, k = i & 127;
    weffT[i] = f2bf(Wint[k * 128 + n] + Wint[(k + 128) * 128 + n]);
  }
}

__global__ void k_prepB(const float* __restrict__ Wself, const float* __restrict__ Wmsg,
                        unsigned short* __restrict__ Bt) {
  int i = blockIdx.x * 256 + threadIdx.x;
  if (i < 128 * 256) {
    int n = i >> 8, k = i & 255;
    float w = (k < HD) ? Wself[k * HD + n] : Wmsg[(k - HD) * HD + n];
    Bt[i] = f2bf(w);
  }
}

__global__ void k_prepIn(const float* __restrict__ Win, const float* __restrict__ Walt,
                         unsigned short* __restrict__ BtIn) {
  int i = blockIdx.x * 256 + threadIdx.x;
  if (i < 2 * 128 * 128) {
    int p = i >> 14; int rem = i & 16383; int n = rem >> 7; int k = rem & 127;
    const float* W = p ? Walt : Win;
    BtIn[i] = f2bf(W[k * 128 + n]);
  }
}

// ---------------- init (MFMA): writes hbf only ----------------
__global__ __launch_bounds__(256) void k_init2(
    const float* __restrict__ x, const unsigned short* __restrict__ BtIn,
    const float* __restrict__ bin, const float* __restrict__ gin, const float* __restrict__ bein,
    const float* __restrict__ balt, const float* __restrict__ galt, const float* __restrict__ bealt,
    const float* __restrict__ alphap, const float* __restrict__ betap,
    unsigned short* __restrict__ hbf)
{
  __shared__ float red[4][16][2];
  __shared__ unsigned short gtile[2][16][64];
  int tid = threadIdx.x;
  int wave = tid >> 6;
  int lane = tid & 63;
  int l15 = lane & 15;
  int lhi = lane >> 4;
  int path = wave >> 1;
  int colBase = (wave & 1) * 64;
  int rowBase = blockIdx.x * 64;

  const unsigned short* Bp = BtIn + path * 128 * 128;
  short8v bfr[4][4];
#pragma unroll
  for (int t = 0; t < 4; ++t) {
    int n = colBase + t * 16 + l15;
#pragma unroll
    for (int s = 0; s < 4; ++s)
      bfr[t][s] = *(const short8v*)&Bp[n * 128 + s * 32 + lhi * 8];
  }

  const float* bvp = path ? balt : bin;
  const float* gp  = path ? galt : gin;
  const float* bep = path ? bealt : bein;
  float bv[4], gw[4], bew[4];
#pragma unroll
  for (int t = 0; t < 4; ++t) {
    int col = colBase + t * 16 + l15;
    bv[t] = bvp[col]; gw[t] = gp[col]; bew[t] = bep[col];
  }

  float al = alphap[0], btv = betap[0];
  float nrm = sqrtf(al * al + btv * btv);
  float w0 = fabsf(al) / nrm, w1 = fabsf(btv) / nrm;

  for (int rt = 0; rt < 4; ++rt) {
    int arow = rowBase + rt * 16 + l15; if (arow >= NND) arow = NND - 1;
    short8v afr[4];
#pragma unroll
    for (int s = 0; s < 4; ++s) {
      float4 xa = *(const float4*)&x[(size_t)arow * HD + s * 32 + lhi * 8];
      float4 xb = *(const float4*)&x[(size_t)arow * HD + s * 32 + lhi * 8 + 4];
      short8v f;
      f[0] = (short)f2bf(xa.x); f[1] = (short)f2bf(xa.y);
      f[2] = (short)f2bf(xa.z); f[3] = (short)f2bf(xa.w);
      f[4] = (short)f2bf(xb.x); f[5] = (short)f2bf(xb.y);
      f[6] = (short)f2bf(xb.z); f[7] = (short)f2bf(xb.w);
      afr[s] = f;
    }

    float4v acc[4];
#pragma unroll
    for (int t = 0; t < 4; ++t) acc[t] = (float4v){0.f, 0.f, 0.f, 0.f};
#pragma unroll
    for (int s = 0; s < 4; ++s) {
#pragma unroll
      for (int t = 0; t < 4; ++t)
        acc[t] = __builtin_amdgcn_mfma_f32_16x16x32_bf16(afr[s], bfr[t][s], acc[t], 0, 0, 0);
    }

    float z[4][4];
    float psum[4], psq[4];
#pragma unroll
    for (int r = 0; r < 4; ++r) {
      float s1 = 0.f, s2 = 0.f;
#pragma unroll
      for (int t = 0; t < 4; ++t) {
        float zz = acc[t][r] + bv[t];
        z[r][t] = zz;
        s1 += zz; s2 += zz * zz;
      }
#pragma unroll
      for (int m = 1; m < 16; m <<= 1) {
        s1 += __shfl_xor(s1, m, 16);
        s2 += __shfl_xor(s2, m, 16);
      }
      psum[r] = s1; psq[r] = s2;
    }
    if (l15 == 0) {
#pragma unroll
      for (int r = 0; r < 4; ++r) {
        red[wave][lhi * 4 + r][0] = psum[r];
        red[wave][lhi * 4 + r][1] = psq[r];
      }
    }
    __syncthreads();

    int pw = wave ^ 1;
    float gval[4][4];
#pragma unroll
    for (int r = 0; r < 4; ++r) {
      int rowl = lhi * 4 + r;
      float S = psum[r] + red[pw][rowl][0];
      float Q = psq[r]  + red[pw][rowl][1];
      float mean = S * (1.0f / 128.0f);
      float var  = Q * (1.0f / 128.0f) - mean * mean;
      float rs = rsqrtf(var + 1e-5f);
#pragma unroll
      for (int t = 0; t < 4; ++t)
        gval[r][t] = gelu_t((z[r][t] - mean) * rs * gw[t] + bew[t]);
    }

    if (path == 1) {
#pragma unroll
      for (int r = 0; r < 4; ++r)
#pragma unroll
        for (int t = 0; t < 4; ++t)
          gtile[wave & 1][lhi * 4 + r][t * 16 + l15] = f2bf(gval[r][t]);
    }
    __syncthreads();

    if (path == 0) {
#pragma unroll
      for (int r = 0; r < 4; ++r) {
        int m = rowBase + rt * 16 + lhi * 4 + r;
        if (m < NND) {
#pragma unroll
          for (int t = 0; t < 4; ++t) {
            float g1 = bf2f(gtile[wave & 1][lhi * 4 + r][t * 16 + l15]);
            float hv = w0 * gval[r][t] + w1 * g1;
            hbf[(size_t)m * HD + colBase + t * 16 + l15] = f2bf(hv);
          }
        }
      }
    }
    __syncthreads();
  }
}

// ---------------- gather kernel ----------------
// mode 0: u = meanagg(hbf); usav = u     (step-0 stage-0)
// mode 1: usav += meanagg(dh8)/8; u = usav  (stage-0 later steps)
// mode 2: u = usav + cu*meanagg(t8)         (stages 1-3)
__global__ __launch_bounds__(256) void k_gath2(
    const unsigned short* __restrict__ hbf,
    const unsigned char*  __restrict__ t8,
    unsigned short* __restrict__ usav,
    unsigned short* __restrict__ uT,
    const int* __restrict__ rowptr,
    const unsigned short* __restrict__ cs16,
    const float* __restrict__ deginv,
    int mode, float cu)
{
  int tid = threadIdx.x;
  int l16 = tid & 15;
  int grp = tid >> 4;
  int node = blockIdx.x * 16 + grp;
  if (node >= NND) return;
  int e0 = rowptr[node], e1 = rowptr[node + 1];
  float a0=0,a1=0,a2=0,a3=0,a4=0,a5=0,a6=0,a7=0;

  if (mode == 0) {
    for (int eb = e0; eb < e1; eb += 16) {
      int rem = e1 - eb;
      int ia = eb + l16; if (ia > e1 - 1) ia = e1 - 1;
      int my = cs16[ia];
      int n16 = (rem < 16) ? rem : 16;
#pragma unroll
      for (int j = 0; j < 16; ++j) {
        if (j < n16) {
          int s = __shfl(my, j, 16);
          uint4 v = *(const uint4*)&hbf[(size_t)s * HD + l16 * 8];
          a0 += bflo(v.x); a1 += bfhi(v.x); a2 += bflo(v.y); a3 += bfhi(v.y);
          a4 += bflo(v.z); a5 += bfhi(v.z); a6 += bflo(v.w); a7 += bfhi(v.w);
        }
      }
    }
  } else {
    for (int eb = e0; eb < e1; eb += 16) {
      int rem = e1 - eb;
      int ia = eb + l16; if (ia > e1 - 1) ia = e1 - 1;
      int my = cs16[ia];
      int n16 = (rem < 16) ? rem : 16;
      uint2 v[16];
#pragma unroll
      for (int j = 0; j < 16; ++j) {
        if (j < n16) {
          int s = __shfl(my, j, 16);
          v[j] = *(const uint2*)&t8[(size_t)s * HD + l16 * 8];
        }
      }
#pragma unroll
      for (int j = 0; j < 16; ++j) {
        if (j < n16) {
          float2v f0 = __builtin_amdgcn_cvt_pk_f32_fp8(v[j].x, false);
          float2v f1 = __builtin_amdgcn_cvt_pk_f32_fp8(v[j].x, true);
          float2v f2 = __builtin_amdgcn_cvt_pk_f32_fp8(v[j].y, false);
          float2v f3 = __builtin_amdgcn_cvt_pk_f32_fp8(v[j].y, true);
          a0 += f0[0]; a1 += f0[1]; a2 += f1[0]; a3 += f1[1];
          a4 += f2[0]; a5 += f2[1]; a6 += f3[0]; a7 += f3[1];
        }
      }
    }
  }

  float sc = deginv[node] * ((mode == 0) ? 1.0f : ((mode == 1) ? 0.125f : cu));
  size_t base = (size_t)node * HD + l16 * 8;
  float u0,u1,u2,u3,u4,u5,u6,u7;
  if (mode == 0) {
    u0=a0*sc; u1=a1*sc; u2=a2*sc; u3=a3*sc; u4=a4*sc; u5=a5*sc; u6=a6*sc; u7=a7*sc;
  } else {
    uint4 us = *(const uint4*)&usav[base];
    u0 = bflo(us.x) + a0*sc; u1 = bfhi(us.x) + a1*sc;
    u2 = bflo(us.y) + a2*sc; u3 = bfhi(us.y) + a3*sc;
    u4 = bflo(us.z) + a4*sc; u5 = bfhi(us.z) + a5*sc;
    u6 = bflo(us.w) + a6*sc; u7 = bfhi(us.w) + a7*sc;
  }
  uint4 o;
  o.x = (unsigned int)f2bf(u0) | ((unsigned int)f2bf(u1) << 16);
  o.y = (unsigned int)f2bf(u2) | ((unsigned int)f2bf(u3) << 16);
  o.z = (unsigned int)f2bf(u4) | ((unsigned int)f2bf(u5) << 16);
  o.w = (unsigned int)f2bf(u6) | ((unsigned int)f2bf(u7) << 16);
  if (mode <= 1) *(uint4*)&usav[base] = o;
  *(uint4*)&uT[base] = o;
}

// ---------------- ODE GEMM (MT=64: B-fragments amortized over 4 row-tiles) ----------------
__global__ __launch_bounds__(256) void k_ode3(
    const unsigned short* __restrict__ hc,
    unsigned short* __restrict__ hn,
    const unsigned short* __restrict__ uT,
    const unsigned char* __restrict__ k8A,
    unsigned char* __restrict__ k8w,
    const unsigned char* __restrict__ k8r0,
    const unsigned char* __restrict__ k8r1,
    const unsigned char* __restrict__ k8r2,
    unsigned char* __restrict__ dh8,
    const unsigned short* __restrict__ Bt, const float* __restrict__ bode,
    int stage, float cyA)
{
  int tid = threadIdx.x;
  int wave = tid >> 6;
  int lane = tid & 63;
  int l15 = lane & 15;
  int lhi = lane >> 4;
  int rowBase = blockIdx.x * MT;
  int ncol0 = wave * 32;

  const float DT = 0.125f;
  const float w6 = DT / 6.0f;

  short8v bfr[2][8];
#pragma unroll
  for (int t = 0; t < 2; ++t) {
    int n = ncol0 + t * 16 + l15;
#pragma unroll
    for (int s = 0; s < 8; ++s) {
      bfr[t][s] = *(const short8v*)&Bt[n * 256 + s * 32 + lhi * 8];
    }
  }
  float4 bo4[2];
  bo4[0] = *(const float4*)&bode[ncol0 + lhi * 4];
  bo4[1] = *(const float4*)&bode[ncol0 + 16 + lhi * 4];

#pragma unroll
  for (int rt = 0; rt < MT / 16; ++rt) {
    int mload = rowBase + rt * 16 + l15;
    if (mload >= NND) mload = NND - 1;
    short8v afr[8];
#pragma unroll
    for (int s = 0; s < 4; ++s) {
      size_t base = (size_t)mload * HD + s * 32 + lhi * 8;
      if (stage == 0) {
        afr[s] = *(const short8v*)&hc[base];
      } else {
        uint4 hv = *(const uint4*)&hc[base];
        uint2 kq = *(const uint2*)&k8A[base];
        float2v f0 = __builtin_amdgcn_cvt_pk_f32_fp8(kq.x, false);
        float2v f1 = __builtin_amdgcn_cvt_pk_f32_fp8(kq.x, true);
        float2v f2 = __builtin_amdgcn_cvt_pk_f32_fp8(kq.y, false);
        float2v f3 = __builtin_amdgcn_cvt_pk_f32_fp8(kq.y, true);
        short8v f;
        f[0] = (short)f2bf(bflo(hv.x) + cyA * f0[0]);
        f[1] = (short)f2bf(bfhi(hv.x) + cyA * f0[1]);
        f[2] = (short)f2bf(bflo(hv.y) + cyA * f1[0]);
        f[3] = (short)f2bf(bfhi(hv.y) + cyA * f1[1]);
        f[4] = (short)f2bf(bflo(hv.z) + cyA * f2[0]);
        f[5] = (short)f2bf(bfhi(hv.z) + cyA * f2[1]);
        f[6] = (short)f2bf(bflo(hv.w) + cyA * f3[0]);
        f[7] = (short)f2bf(bfhi(hv.w) + cyA * f3[1]);
        afr[s] = f;
      }
    }
#pragma unroll
    for (int s = 0; s < 4; ++s)
      afr[4 + s] = *(const short8v*)&uT[(size_t)mload * HD + s * 32 + lhi * 8];

    float4v acc0 = {0.f, 0.f, 0.f, 0.f};
    float4v acc1 = {0.f, 0.f, 0.f, 0.f};
#pragma unroll
    for (int s = 0; s < 8; ++s) {
      acc0 = __builtin_amdgcn_mfma_f32_16x16x32_bf16(bfr[0][s], afr[s], acc0, 0, 0, 0);
      acc1 = __builtin_amdgcn_mfma_f32_16x16x32_bf16(bfr[1][s], afr[s], acc1, 0, 0, 0);
    }

    int m = rowBase + rt * 16 + l15;
    if (m < NND) {
#pragma unroll
      for (int t = 0; t < 2; ++t) {
        int n0 = ncol0 + t * 16 + lhi * 4;
        size_t off = (size_t)m * HD + n0;
        float4v acc = t ? acc1 : acc0;
        float4 bo = bo4[t];
        float kv0 = tanhf(acc[0] + bo.x);
        float kv1 = tanhf(acc[1] + bo.y);
        float kv2 = tanhf(acc[2] + bo.z);
        float kv3 = tanhf(acc[3] + bo.w);
        if (stage < 3) {
          unsigned int p8 = __builtin_amdgcn_cvt_pk_fp8_f32(kv0, kv1, 0u, false);
          p8 = __builtin_amdgcn_cvt_pk_fp8_f32(kv2, kv3, p8, true);
          *(unsigned int*)&k8w[off] = p8;
        } else {
          unsigned int q0 = *(const unsigned int*)&k8r0[off];
          unsigned int q1 = *(const unsigned int*)&k8r1[off];
          unsigned int q2 = *(const unsigned int*)&k8r2[off];
          float2v a0 = __builtin_amdgcn_cvt_pk_f32_fp8(q0, false);
          float2v a1 = __builtin_amdgcn_cvt_pk_f32_fp8(q0, true);
          float2v b0 = __builtin_amdgcn_cvt_pk_f32_fp8(q1, false);
          float2v b1 = __builtin_amdgcn_cvt_pk_f32_fp8(q1, true);
          float2v c0 = __builtin_amdgcn_cvt_pk_f32_fp8(q2, false);
          float2v c1 = __builtin_amdgcn_cvt_pk_f32_fp8(q2, true);
          float dh0 = w6 * (a0[0] + 2.f * b0[0] + 2.f * c0[0] + kv0);
          float dh1 = w6 * (a0[1] + 2.f * b0[1] + 2.f * c0[1] + kv1);
          float dh2 = w6 * (a1[0] + 2.f * b1[0] + 2.f * c1[0] + kv2);
          float dh3 = w6 * (a1[1] + 2.f * b1[1] + 2.f * c1[1] + kv3);
          uint2 hv = *(const uint2*)&hc[off];
          float h0 = bflo(hv.x) + dh0;
          float h1 = bfhi(hv.x) + dh1;
          float h2 = bflo(hv.y) + dh2;
          float h3 = bfhi(hv.y) + dh3;
          uint2 ho;
          ho.x = (unsigned int)f2bf(h0) | ((unsigned int)f2bf(h1) << 16);
          ho.y = (unsigned int)f2bf(h2) | ((unsigned int)f2bf(h3) << 16);
          *(uint2*)&hn[off] = ho;
          unsigned int p8 = __builtin_amdgcn_cvt_pk_fp8_f32(8.0f * dh0, 8.0f * dh1, 0u, false);
          p8 = __builtin_amdgcn_cvt_pk_fp8_f32(8.0f * dh2, 8.0f * dh3, p8, true);
          *(unsigned int*)&dh8[off] = p8;
        }
      }
    }
  }
}

// ---------------- interference (MFMA, swapped operands) ----------------
__global__ __launch_bounds__(256) void k_interf2(
    const unsigned short* __restrict__ hbf, const unsigned short* __restrict__ weffT,
    const float* __restrict__ bint, const float* __restrict__ gint,
    const float* __restrict__ beint,
    const float* __restrict__ alphap, const float* __restrict__ betap,
    const float* __restrict__ phasep,
    unsigned short* __restrict__ h2bf)
{
  __shared__ float red[4][16][2];
  int tid = threadIdx.x;
  int wave = tid >> 6;
  int lane = tid & 63;
  int l15 = lane & 15;
  int lhi = lane >> 4;
  int rowBase = blockIdx.x * 32;
  int ncol0 = wave * 32;

  short8v bfr[2][4];
#pragma unroll
  for (int t = 0; t < 2; ++t) {
    int n = ncol0 + t * 16 + l15;
#pragma unroll
    for (int s = 0; s < 4; ++s)
      bfr[t][s] = *(const short8v*)&weffT[n * 128 + s * 32 + lhi * 8];
  }
  float4 bi4[2], gv4[2], bev4[2];
#pragma unroll
  for (int t = 0; t < 2; ++t) {
    int n0 = ncol0 + t * 16 + lhi * 4;
    bi4[t]  = *(const float4*)&bint[n0];
    gv4[t]  = *(const float4*)&gint[n0];
    bev4[t] = *(const float4*)&beint[n0];
  }

  float al = alphap[0], bt = betap[0], ph = phasep[0];
  float n2 = al*al + bt*bt;
  float p0 = (al*al) / n2, p1 = (bt*bt) / n2;
  float interf = 2.0f * sqrtf(p0 * p1) * cosf(ph);
  float gate = (fabsf(interf) > 0.01f) ? interf : 0.0f;
  float cscale = (p0 > p1) ? 1.0f : cosf(ph);

  for (int rt = 0; rt < 2; ++rt) {
    int mload = rowBase + rt * 16 + l15;
    if (mload >= NND) mload = NND - 1;
    short8v afr[4];
#pragma unroll
    for (int s = 0; s < 4; ++s)
      afr[s] = *(const short8v*)&hbf[(size_t)mload * HD + s * 32 + lhi * 8];

    float4v acc0 = {0.f, 0.f, 0.f, 0.f};
    float4v acc1 = {0.f, 0.f, 0.f, 0.f};
#pragma unroll
    for (int s = 0; s < 4; ++s) {
      acc0 = __builtin_amdgcn_mfma_f32_16x16x32_bf16(bfr[0][s], afr[s], acc0, 0, 0, 0);
      acc1 = __builtin_amdgcn_mfma_f32_16x16x32_bf16(bfr[1][s], afr[s], acc1, 0, 0, 0);
    }

    float z[2][4];
    float s1 = 0.f, s2 = 0.f;
#pragma unroll
    for (int t = 0; t < 2; ++t) {
      float4v acc = t ? acc1 : acc0;
#pragma unroll
      for (int i = 0; i < 4; ++i) {
        float zz = acc[i] + ((const float*)&bi4[t])[i];
        z[t][i] = zz;
        s1 += zz; s2 += zz * zz;
      }
    }
    s1 += __shfl_xor(s1, 16, 64); s2 += __shfl_xor(s2, 16, 64);
    s1 += __shfl_xor(s1, 32, 64); s2 += __shfl_xor(s2, 32, 64);
    if (lhi == 0) { red[wave][l15][0] = s1; red[wave][l15][1] = s2; }
    __syncthreads();
    float S = red[0][l15][0] + red[1][l15][0] + red[2][l15][0] + red[3][l15][0];
    float Q = red[0][l15][1] + red[1][l15][1] + red[2][l15][1] + red[3][l15][1];
    float mean = S * (1.0f / 128.0f);
    float var  = Q * (1.0f / 128.0f) - mean * mean;
    float rs = rsqrtf(var + 1e-5f);

    int m = rowBase + rt * 16 + l15;
    if (m < NND) {
#pragma unroll
      for (int t = 0; t < 2; ++t) {
        size_t off = (size_t)m * HD + ncol0 + t * 16 + lhi * 4;
        uint2 hv = *(const uint2*)&hbf[off];
        float h0 = bflo(hv.x), h1 = bfhi(hv.x), h2 = bflo(hv.y), h3 = bfhi(hv.y);
        float t0 = tanhf((z[t][0]-mean)*rs*((const float*)&gv4[t])[0] + ((const float*)&bev4[t])[0]);
        float t1 = tanhf((z[t][1]-mean)*rs*((const float*)&gv4[t])[1] + ((const float*)&bev4[t])[1]);
        float t2 = tanhf((z[t][2]-mean)*rs*((const float*)&gv4[t])[2] + ((const float*)&bev4[t])[2]);
        float t3 = tanhf((z[t][3]-mean)*rs*((const float*)&gv4[t])[3] + ((const float*)&bev4[t])[3]);
        float o0 = (h0 + gate*t0) * cscale;
        float o1 = (h1 + gate*t1) * cscale;
        float o2 = (h2 + gate*t2) * cscale;
        float o3 = (h3 + gate*t3) * cscale;
        uint2 oo;
        oo.x = (unsigned int)f2bf(o0) | ((unsigned int)f2bf(o1) << 16);
        oo.y = (unsigned int)f2bf(o2) | ((unsigned int)f2bf(o3) << 16);
        *(uint2*)&h2bf[off] = oo;
      }
    }
    __syncthreads();
  }
}

// ---------------- per-graph row-sum (one block per graph, no atomics) ----------------
__global__ __launch_bounds__(256) void k_rowsum(
    const unsigned short* __restrict__ h2bf, const int* __restrict__ rowstart,
    float* __restrict__ sg)
{
  __shared__ float red[8][128];
  int g = blockIdx.x;
  int r0 = rowstart[g], r1 = rowstart[g + 1];
  int colq = threadIdx.x & 31;
  int rowp = threadIdx.x >> 5;
  float a0 = 0.f, a1 = 0.f, a2 = 0.f, a3 = 0.f;
  for (int r = r0 + rowp; r < r1; r += 8) {
    uint2 v = *(const uint2*)&h2bf[(size_t)r * HD + colq * 4];
    a0 += bflo(v.x); a1 += bfhi(v.x); a2 += bflo(v.y); a3 += bfhi(v.y);
  }
  red[rowp][colq * 4 + 0] = a0;
  red[rowp][colq * 4 + 1] = a1;
  red[rowp][colq * 4 + 2] = a2;
  red[rowp][colq * 4 + 3] = a3;
  __syncthreads();
  if (rowp == 0) {
#pragma unroll
    for (int i = 0; i < 4; ++i) {
      int c = colq * 4 + i;
      float s = red[0][c] + red[1][c] + red[2][c] + red[3][c]
              + red[4][c] + red[5][c] + red[6][c] + red[7][c];
      sg[g * HD + c] = s;
    }
  }
}

// ---------------- tiny pool GEMM ----------------
__global__ __launch_bounds__(128) void k_pool(
    const float* __restrict__ sg, const float* __restrict__ Wout,
    const float* __restrict__ bout, const float* __restrict__ cnt,
    float* __restrict__ out)
{
  __shared__ float srow[128];
  int g = blockIdx.x;
  int c = threadIdx.x;
  srow[c] = sg[g * HD + c];
  __syncthreads();
  float s = 0.f;
  for (int k = 0; k < 128; ++k) s += srow[k] * Wout[k * HD + c];
  float cg = cnt[g];
  out[g * HD + c] = (s + cg * bout[c]) / fmaxf(cg, 1.0f);
}

extern "C" void kernel_launch(void* const* d_in, const int* in_sizes, int n_in,
                              void* d_out, int out_size, void* d_ws, size_t ws_size,
                              hipStream_t stream) {
  (void)in_sizes; (void)n_in; (void)out_size; (void)ws_size;
  const float* x     = (const float*)d_in[0];
  const int*   ei    = (const int*)d_in[1];
  const int*   batch = (const int*)d_in[2];
  const float* alpha = (const float*)d_in[3];
  const float* beta  = (const float*)d_in[4];
  const float* phase = (const float*)d_in[5];
  const float* Win   = (const float*)d_in[6];
  const float* bin   = (const float*)d_in[7];
  const float* gin   = (const float*)d_in[8];
  const float* bein  = (const float*)d_in[9];
  const float* Walt  = (const float*)d_in[10];
  const float* balt  = (const float*)d_in[11];
  const float* galt  = (const float*)d_in[12];
  const float* bealt = (const float*)d_in[13];
  const float* Wself = (const float*)d_in[14];
  const float* Wmsg  = (const float*)d_in[15];
  const float* bode  = (const float*)d_in[16];
  const float* Wint  = (const float*)d_in[17];
  const float* bint  = (const float*)d_in[18];
  const float* gint  = (const float*)d_in[19];
  const float* beint = (const float*)d_in[20];
  const float* Wout  = (const float*)d_in[21];
  const float* bout  = (const float*)d_in[22];
  float* out = (float*)d_out;

  const int* esrc = ei;
  const int* edst = ei + NED;

  size_t NH = (size_t)NND * HD;   // 6,400,000
  float* deginv = (float*)d_ws;
  float* cnt    = deginv + NND;
  float* sg     = cnt + NG;
  unsigned short* hA    = (unsigned short*)(sg + NG * HD);
  unsigned short* hB    = hA + NH;
  unsigned short* usav  = hB + NH;
  unsigned short* uT    = usav + NH;
  unsigned short* h2bf  = uT + NH;
  unsigned short* Bt    = h2bf + NH;          // 128*256
  unsigned short* BtIn  = Bt + 128 * 256;     // 2*128*128
  unsigned short* weffT = BtIn + 2 * 128 * 128;  // 128*128
  unsigned short* cs16  = weffT + 128 * 128;     // NED
  unsigned char* k80 = (unsigned char*)(cs16 + NED);
  unsigned char* k81 = k80 + NH;
  unsigned char* k82 = k81 + NH;
  unsigned char* dh8 = k82 + NH;
  int* degi     = (int*)(dh8 + NH);
  int* rowptr   = degi + NND;
  int* cursor   = rowptr + (NND + 4);
  int* rowstart = cursor + NND;

  hipMemsetAsync(degi, 0, NND * sizeof(int), stream);

  k_hist   <<<(NED + 255) / 256, 256, 0, stream>>>(edst, degi);
  k_scan   <<<1, 1024, 0, stream>>>(degi, rowptr, cursor, deginv);
  k_scatter<<<(NED + 255) / 256, 256, 0, stream>>>(esrc, edst, cursor, cs16);
  k_cnt    <<<1, 64, 0, stream>>>(batch, cnt, rowstart);
  k_weffT  <<<64, 256, 0, stream>>>(Wint, weffT);
  k_prepB  <<<128, 256, 0, stream>>>(Wself, Wmsg, Bt);
  k_prepIn <<<128, 256, 0, stream>>>(Win, Walt, BtIn);
  k_init2  <<<(NND + 63) / 64, 256, 0, stream>>>(x, BtIn, bin, gin, bein,
                                                 balt, galt, bealt,
                                                 alpha, beta, hA);

  const float DT = 0.125f;
  int gg = (NND + 15) / 16;     // 3125
  int ob = (NND + MT - 1) / MT; // 782
  unsigned short* hcur = hA;
  unsigned short* hnext = hB;
  for (int step = 0; step < 8; ++step) {
    // stage 0: gather (step0: full bf16 h; else incremental dh8); k0 -> k80
    k_gath2<<<gg, 256, 0, stream>>>(hcur, dh8, usav, uT, rowptr, cs16, deginv,
                                    (step == 0) ? 0 : 1, 0.f);
    k_ode3 <<<ob, 256, 0, stream>>>(hcur, hnext, uT, k80, k80, k80, k81, k82, dh8,
                                    Bt, bode, 0, 0.f);
    // stage 1: gather k80; A = h + dt/2*k80; k1 -> k81
    k_gath2<<<gg, 256, 0, stream>>>(hcur, k80, usav, uT, rowptr, cs16, deginv, 2, 0.5f * DT);
    k_ode3 <<<ob, 256, 0, stream>>>(hcur, hnext, uT, k80, k81, k80, k81, k82, dh8,
                                    Bt, bode, 1, 0.5f * DT);
    // stage 2: gather k81; A = h + dt/2*k81; k2 -> k82
    k_gath2<<<gg, 256, 0, stream>>>(hcur, k81, usav, uT, rowptr, cs16, deginv, 2, 0.5f * DT);
    k_ode3 <<<ob, 256, 0, stream>>>(hcur, hnext, uT, k81, k82, k80, k81, k82, dh8,
                                    Bt, bode, 2, 0.5f * DT);
    // stage 3: gather k82; A = h + dt*k82; h update -> hnext; dh8 emit
    k_gath2<<<gg, 256, 0, stream>>>(hcur, k82, usav, uT, rowptr, cs16, deginv, 2, DT);
    k_ode3 <<<ob, 256, 0, stream>>>(hcur, hnext, uT, k82, k80, k80, k81, k82, dh8,
                                    Bt, bode, 3, DT);
    unsigned short* tmp = hcur; hcur = hnext; hnext = tmp;
  }
  k_interf2<<<(NND + 31) / 32, 256, 0, stream>>>(hcur, weffT, bint, gint, beint,
                                                 alpha, beta, phase, h2bf);
  k_rowsum<<<NG, 256, 0, stream>>>(h2bf, rowstart, sg);
  k_pool  <<<NG, 128, 0, stream>>>(sg, Wout, bout, cnt, out);
}